// Round 2
// baseline (2539.326 us; speedup 1.0000x reference)
//
#include <hip/hip_runtime.h>

#define NROWS 32768
#define DIM   128
#define KCODES 4096
#define DECAYF 0.8f
#define EPSF 1e-5f
#define COMMITW 0.25f
#define KSPLIT 4
#define KPER (KCODES / KSPLIT)   // 1024 codes per block
#define ROWBLKS (NROWS / 64)     // 512

// ---------------- e2[k] = sum_d embed[k][d]^2 ----------------
__global__ __launch_bounds__(256) void e2_kernel(const float* __restrict__ embed,
                                                 float* __restrict__ e2) {
    int gid = blockIdx.x * blockDim.x + threadIdx.x;
    int wave = gid >> 6, lane = gid & 63;
    if (wave >= KCODES) return;
    float2 v = ((const float2*)(embed + (size_t)wave * DIM))[lane];
    float s = v.x * v.x + v.y * v.y;
    #pragma unroll
    for (int off = 32; off > 0; off >>= 1) s += __shfl_down(s, off, 64);
    if (lane == 0) e2[wave] = s;
}

// ---------------- argmax: register-resident, barrier-free ----------------
// Grid 2048 = 512 row-tiles x 4 K-splits (ks major: blocks sharing an x-tile
// are 512 apart -> same XCD since 512 % 8 == 0). 128 threads: tx=tid&7 codes,
// ty=tid>>3 rows. Micro-tile 4 rows (ty+16i) x 4 codes (tx+8j). All loads
// global float4; 8 lanes share each address (wave-level broadcast merge).
// No LDS, no __syncthreads.
__global__ __launch_bounds__(128) void argmax_kernel(const float* __restrict__ x,
                                                     const float* __restrict__ embed,
                                                     const float* __restrict__ e2,
                                                     float2* __restrict__ partial) {
    int tid = threadIdx.x;
    int tx = tid & 7;
    int ty = tid >> 3;
    int bt = blockIdx.x;
    int rowblk = bt & (ROWBLKS - 1);
    int ks = bt >> 9;               // 0..3
    int n0 = rowblk * 64;
    int c0 = ks * KPER;

    const float* xbase = x + (size_t)(n0 + ty) * DIM;   // + i*16*DIM per i

    float best[4];
    int   bidx[4];
    #pragma unroll
    for (int i = 0; i < 4; i++) { best[i] = -3.0e38f; bidx[i] = 0; }

    for (int kc = 0; kc < KPER / 32; kc++) {
        int cbase = c0 + kc * 32 + tx;                  // + 8j per j
        const float* ebase = embed + (size_t)cbase * DIM;

        float acc[4][4];
        #pragma unroll
        for (int i = 0; i < 4; i++)
            #pragma unroll
            for (int j = 0; j < 4; j++) acc[i][j] = 0.f;

        #pragma unroll 8
        for (int d4 = 0; d4 < DIM / 4; d4++) {
            float4 xv[4], ev[4];
            #pragma unroll
            for (int i = 0; i < 4; i++)
                xv[i] = *(const float4*)(xbase + i * 16 * DIM + d4 * 4);
            #pragma unroll
            for (int j = 0; j < 4; j++)
                ev[j] = *(const float4*)(ebase + j * 8 * DIM + d4 * 4);
            #pragma unroll
            for (int i = 0; i < 4; i++)
                #pragma unroll
                for (int j = 0; j < 4; j++) {
                    float a = acc[i][j];
                    a = fmaf(xv[i].x, ev[j].x, a);
                    a = fmaf(xv[i].y, ev[j].y, a);
                    a = fmaf(xv[i].z, ev[j].z, a);
                    a = fmaf(xv[i].w, ev[j].w, a);
                    acc[i][j] = a;
                }
        }

        // codes ascend with j and kc -> strict > keeps lowest index on ties
        #pragma unroll
        for (int j = 0; j < 4; j++) {
            int c = cbase + 8 * j;
            float ec = e2[c];
            #pragma unroll
            for (int i = 0; i < 4; i++) {
                float m = 2.0f * acc[i][j] - ec;
                if (m > best[i]) { best[i] = m; bidx[i] = c; }
            }
        }
    }

    // reduce across tx (8 consecutive lanes share a ty)
    #pragma unroll
    for (int i = 0; i < 4; i++) {
        float bv = best[i];
        int   bi = bidx[i];
        #pragma unroll
        for (int off = 4; off > 0; off >>= 1) {
            float ov = __shfl_down(bv, off, 8);
            int   oi = __shfl_down(bi, off, 8);
            if (ov > bv || (ov == bv && oi < bi)) { bv = ov; bi = oi; }
        }
        if (tx == 0) {
            int row = n0 + ty + 16 * i;
            float2 p;
            p.x = bv;
            p.y = __int_as_float(bi);
            partial[(size_t)row * KSPLIT + ks] = p;
        }
    }
}

// ---------------- merge K-split partials ----------------
__global__ __launch_bounds__(256) void merge_kernel(const float2* __restrict__ partial,
                                                    int* __restrict__ ind,
                                                    float* __restrict__ out_ind) {
    int row = blockIdx.x * 256 + threadIdx.x;
    float bv = -3.0e38f;
    int   bi = 1 << 30;
    #pragma unroll
    for (int s = 0; s < KSPLIT; s++) {       // s ascending = codes ascending
        float2 p = partial[(size_t)row * KSPLIT + s];
        int pi = __float_as_int(p.y);
        if (p.x > bv || (p.x == bv && pi < bi)) { bv = p.x; bi = pi; }
    }
    ind[row] = bi;
    out_ind[row] = (float)bi;
}

// ---------------- gather quantize, scatter stats, commit loss ----------------
__global__ __launch_bounds__(256) void scatter_kernel(const float* __restrict__ x,
                                                      const float* __restrict__ embed,
                                                      const int* __restrict__ ind,
                                                      float* __restrict__ out_q,
                                                      float* __restrict__ bins,
                                                      float* __restrict__ esum,
                                                      float* __restrict__ loss,
                                                      int pmask) {
    int tid = threadIdx.x;
    int row = blockIdx.x * 2 + (tid >> 7);
    int d   = tid & 127;
    int p   = blockIdx.x & pmask;
    int k   = ind[row];
    float q  = embed[(size_t)k * DIM + d];
    float xv = x[(size_t)row * DIM + d];
    out_q[(size_t)row * DIM + d] = q;
    if (d == 0) atomicAdd(&bins[p * KCODES + k], 1.0f);
    atomicAdd(&esum[(size_t)p * KCODES * DIM + (size_t)k * DIM + d], xv);
    float diff = q - xv;
    float s = diff * diff;
    #pragma unroll
    for (int off = 32; off > 0; off >>= 1) s += __shfl_down(s, off, 64);
    __shared__ float ls[4];
    if ((tid & 63) == 0) ls[tid >> 6] = s;
    __syncthreads();
    if (tid == 0) atomicAdd(loss, ls[0] + ls[1] + ls[2] + ls[3]);
}

// ---------------- cs_new + n_total ----------------
__global__ __launch_bounds__(256) void cs_kernel(const float* __restrict__ cluster_size,
                                                 const float* __restrict__ bins,
                                                 float* __restrict__ out_cs,
                                                 float* __restrict__ ntot,
                                                 int ncopy) {
    int k = blockIdx.x * 256 + threadIdx.x;
    float b = 0.f;
    for (int p = 0; p < ncopy; p++) b += bins[p * KCODES + k];
    float cs = cluster_size[k] * DECAYF + (1.0f - DECAYF) * b;
    out_cs[k] = cs;
    float s = cs;
    #pragma unroll
    for (int off = 32; off > 0; off >>= 1) s += __shfl_down(s, off, 64);
    __shared__ float ls[4];
    if ((threadIdx.x & 63) == 0) ls[threadIdx.x >> 6] = s;
    __syncthreads();
    if (threadIdx.x == 0) atomicAdd(ntot, ls[0] + ls[1] + ls[2] + ls[3]);
}

// ---------------- embed_normalized + commit_loss finalize ----------------
__global__ __launch_bounds__(128) void norm_kernel(const float* __restrict__ embed_avg,
                                                   const float* __restrict__ esum,
                                                   const float* __restrict__ out_cs,
                                                   const float* __restrict__ ntot,
                                                   const float* __restrict__ loss,
                                                   float* __restrict__ out_norm,
                                                   float* __restrict__ out_loss,
                                                   int ncopy) {
    int k = blockIdx.x;
    int d = threadIdx.x;
    float nt = *ntot;
    float cs = out_cs[k];
    float cluster = (cs + EPSF) / (nt + (float)KCODES * EPSF) * nt;
    size_t idx = (size_t)k * DIM + d;
    float es = 0.f;
    for (int p = 0; p < ncopy; p++) es += esum[(size_t)p * KCODES * DIM + idx];
    float ea = embed_avg[idx] * DECAYF + (1.0f - DECAYF) * es;
    out_norm[idx] = ea / cluster;
    if (k == 0 && d == 0) {
        *out_loss = COMMITW * (*loss) / (float)((size_t)NROWS * DIM);
    }
}

extern "C" void kernel_launch(void* const* d_in, const int* in_sizes, int n_in,
                              void* d_out, int out_size, void* d_ws, size_t ws_size,
                              hipStream_t stream) {
    const float* x            = (const float*)d_in[0];
    const float* embed        = (const float*)d_in[1];
    const float* cluster_size = (const float*)d_in[2];
    const float* embed_avg    = (const float*)d_in[3];

    float* out      = (float*)d_out;
    float* out_q    = out;                               // 4194304
    float* out_ind  = out + 4194304;                     // 32768
    float* out_loss = out_ind + 32768;                   // 1
    float* out_cs   = out_loss + 1;                      // 4096
    float* out_norm = out_cs + 4096;                     // 524288

    // workspace layout
    char* ws = (char*)d_ws;
    int*    ind     = (int*)ws;                          // 131072 B
    float*  e2      = (float*)(ws + 131072);             // 16384 B
    float2* partial = (float2*)(ws + 147456);            // 32768*4*8 = 1048576 B
    float*  loss    = (float*)(ws + 1196032);            // 4 B
    float*  ntot    = loss + 1;                          // 4 B (pad to 256)
    float*  bins    = (float*)(ws + 1196288);            // ncopy * 16384 B
    // esum follows bins
    size_t need8 = 1196288 + 8ull * (16384 + 2097152);
    int ncopy = (ws_size >= need8) ? 8 : 1;
    float*  esum = (float*)(ws + 1196288 + (size_t)ncopy * 16384);

    // zero loss/ntot/pad + bins + esum in one memset (contiguous)
    hipMemsetAsync(ws + 1196032, 0,
                   256 + (size_t)ncopy * 16384 + (size_t)ncopy * 2097152, stream);

    e2_kernel<<<KCODES * 64 / 256, 256, 0, stream>>>(embed, e2);
    argmax_kernel<<<ROWBLKS * KSPLIT, 128, 0, stream>>>(x, embed, e2, partial);
    merge_kernel<<<NROWS / 256, 256, 0, stream>>>(partial, ind, out_ind);
    scatter_kernel<<<NROWS / 2, 256, 0, stream>>>(x, embed, ind, out_q,
                                                  bins, esum, loss, ncopy - 1);
    cs_kernel<<<KCODES / 256, 256, 0, stream>>>(cluster_size, bins, out_cs, ntot, ncopy);
    norm_kernel<<<KCODES, 128, 0, stream>>>(embed_avg, esum, out_cs, ntot, loss,
                                            out_norm, out_loss, ncopy);
}

// Round 3
// 982.547 us; speedup vs baseline: 2.5844x; 2.5844x over previous
//
#include <hip/hip_runtime.h>

#define NROWS 32768
#define DIM   128
#define KCODES 4096
#define DECAYF 0.8f
#define EPSF 1e-5f
#define COMMITW 0.25f

typedef __attribute__((ext_vector_type(8))) short short8;
typedef __attribute__((ext_vector_type(4))) short short4v;
typedef __attribute__((ext_vector_type(4))) float float4v;

// bf16 round-to-nearest-even; returns bits, sets back = exact fp32 value
static __device__ inline short bf16rn(float f, float& back) {
    unsigned u = __float_as_uint(f);
    unsigned r = (u + 0x7FFFu + ((u >> 16) & 1u)) & 0xFFFF0000u;
    back = __uint_as_float(r);
    return (short)(r >> 16);
}

// ---------------- embed -> 3-way bf16 split planes ----------------
__global__ __launch_bounds__(256) void split_kernel(const float* __restrict__ embed,
                                                    short* __restrict__ ehi,
                                                    short* __restrict__ emid,
                                                    short* __restrict__ elo) {
    int gid = blockIdx.x * 256 + threadIdx.x;   // 0 .. KCODES*DIM-1
    float f = embed[gid];
    float hb, mb, db;
    short hs = bf16rn(f, hb);
    float r1 = f - hb;
    short ms = bf16rn(r1, mb);
    float r2 = r1 - mb;
    short ls = bf16rn(r2, db);
    ehi[gid] = hs; emid[gid] = ms; elo[gid] = ls;
}

// ---------------- e2h[k] = 0.5 * sum_d embed[k][d]^2 ----------------
__global__ __launch_bounds__(256) void e2_kernel(const float* __restrict__ embed,
                                                 float* __restrict__ e2h) {
    int gid = blockIdx.x * blockDim.x + threadIdx.x;
    int wave = gid >> 6, lane = gid & 63;
    if (wave >= KCODES) return;
    float2 v = ((const float2*)(embed + (size_t)wave * DIM))[lane];
    float s = v.x * v.x + v.y * v.y;
    #pragma unroll
    for (int off = 32; off > 0; off >>= 1) s += __shfl_down(s, off, 64);
    if (lane == 0) e2h[wave] = 0.5f * s;
}

// ---------------- MFMA argmax: 64 rows/block, full code sweep ----------------
// score = x.e - 0.5*|e|^2 (monotone in -dist). 6-term split-bf16 product keeps
// fp32-level accuracy. A-frags register-resident; B register-prefetched from
// L2-hot split-embed. One barrier total. C layout: row=(lane>>4)*4+reg,
// col=lane&15 (m89-verified).
__global__ __launch_bounds__(256, 2) void argmax_kernel(const float* __restrict__ x,
                                                        const short* __restrict__ ehi,
                                                        const short* __restrict__ emid,
                                                        const short* __restrict__ elo,
                                                        const float* __restrict__ e2h,
                                                        int* __restrict__ ind,
                                                        float* __restrict__ out_ind) {
    __shared__ short xs[3][64][136];   // +8 pad: conflict-free b128 frag reads
    int tid = threadIdx.x;
    int lane = tid & 63;
    int w = tid >> 6;                  // wave -> row-tile
    int n0 = blockIdx.x * 64;
    int m15 = lane & 15;
    int q = lane >> 4;

    // stage x tile, splitting fp32 -> hi/mid/lo bf16
    #pragma unroll
    for (int t = 0; t < 8; ++t) {
        int idx = tid + t * 256;
        int row = idx >> 5, c4 = idx & 31;
        float4 v = ((const float4*)(x + (size_t)(n0 + row) * DIM))[c4];
        float f[4] = {v.x, v.y, v.z, v.w};
        short4v H, M, L;
        #pragma unroll
        for (int e = 0; e < 4; ++e) {
            float hb, mb, db;
            short hs = bf16rn(f[e], hb);
            float r1 = f[e] - hb;
            short ms = bf16rn(r1, mb);
            float r2 = r1 - mb;
            short ls = bf16rn(r2, db);
            H[e] = hs; M[e] = ms; L[e] = ls;
        }
        *(short4v*)&xs[0][row][c4 * 4] = H;
        *(short4v*)&xs[1][row][c4 * 4] = M;
        *(short4v*)&xs[2][row][c4 * 4] = L;
    }
    __syncthreads();

    // A-frags for this wave's 16 rows: resident for the whole sweep
    short8 Ah[4], Am[4], Al[4];
    #pragma unroll
    for (int ks = 0; ks < 4; ++ks) {
        int col = ks * 32 + q * 8;
        Ah[ks] = *(const short8*)&xs[0][w * 16 + m15][col];
        Am[ks] = *(const short8*)&xs[1][w * 16 + m15][col];
        Al[ks] = *(const short8*)&xs[2][w * 16 + m15][col];
    }

    float4v acc[4];
    short8 Bc[4][3], Bn[4][3];
    float e2c[4], e2n[4];
    float best[4];
    int   bidx[4];
    #pragma unroll
    for (int r = 0; r < 4; ++r) { best[r] = -3.0e38f; bidx[r] = 0; }

    #define BOFF(c0_, j_, k0_) ((size_t)((c0_) + (j_) * 16 + m15) * DIM + (k0_) + q * 8)

    #pragma unroll
    for (int j = 0; j < 4; ++j) {
        size_t o = BOFF(0, j, 0);
        Bc[j][0] = *(const short8*)(ehi + o);
        Bc[j][1] = *(const short8*)(emid + o);
        Bc[j][2] = *(const short8*)(elo + o);
        e2c[j] = e2h[j * 16 + m15];
        acc[j] = (float4v){0.f, 0.f, 0.f, 0.f};
    }

    for (int chunk = 0; chunk < 64; ++chunk) {
        int c0 = chunk * 64;
        #pragma unroll
        for (int ks = 0; ks < 4; ++ks) {
            // prefetch next k-step's B frags (and next chunk's e2)
            if (!(chunk == 63 && ks == 3)) {
                int nc0 = (ks == 3) ? c0 + 64 : c0;
                int nk0 = ((ks + 1) & 3) * 32;
                #pragma unroll
                for (int j = 0; j < 4; ++j) {
                    size_t o = BOFF(nc0, j, nk0);
                    Bn[j][0] = *(const short8*)(ehi + o);
                    Bn[j][1] = *(const short8*)(emid + o);
                    Bn[j][2] = *(const short8*)(elo + o);
                }
                if (ks == 3) {
                    #pragma unroll
                    for (int j = 0; j < 4; ++j) e2n[j] = e2h[nc0 + j * 16 + m15];
                }
            }
            // 24 MFMAs: 6 split products x 4 code-tiles
            #pragma unroll
            for (int j = 0; j < 4; ++j) {
                acc[j] = __builtin_amdgcn_mfma_f32_16x16x32_bf16(Ah[ks], Bc[j][0], acc[j], 0, 0, 0);
                acc[j] = __builtin_amdgcn_mfma_f32_16x16x32_bf16(Ah[ks], Bc[j][1], acc[j], 0, 0, 0);
                acc[j] = __builtin_amdgcn_mfma_f32_16x16x32_bf16(Am[ks], Bc[j][0], acc[j], 0, 0, 0);
                acc[j] = __builtin_amdgcn_mfma_f32_16x16x32_bf16(Ah[ks], Bc[j][2], acc[j], 0, 0, 0);
                acc[j] = __builtin_amdgcn_mfma_f32_16x16x32_bf16(Al[ks], Bc[j][0], acc[j], 0, 0, 0);
                acc[j] = __builtin_amdgcn_mfma_f32_16x16x32_bf16(Am[ks], Bc[j][1], acc[j], 0, 0, 0);
            }
            if (ks == 3) {
                // codes ascend with j and chunk -> strict > keeps lowest index
                #pragma unroll
                for (int j = 0; j < 4; ++j) {
                    int c = c0 + j * 16 + m15;
                    #pragma unroll
                    for (int r = 0; r < 4; ++r) {
                        float s = acc[j][r] - e2c[j];
                        if (s > best[r]) { best[r] = s; bidx[r] = c; }
                    }
                    acc[j] = (float4v){0.f, 0.f, 0.f, 0.f};
                    e2c[j] = e2n[j];
                }
            }
            #pragma unroll
            for (int j = 0; j < 4; ++j) {
                Bc[j][0] = Bn[j][0]; Bc[j][1] = Bn[j][1]; Bc[j][2] = Bn[j][2];
            }
        }
    }

    // reduce across the 16 lanes sharing rows (cols); min index on ties
    #pragma unroll
    for (int r = 0; r < 4; ++r) {
        float bv = best[r];
        int   bi = bidx[r];
        #pragma unroll
        for (int m = 1; m <= 8; m <<= 1) {
            float ov = __shfl_xor(bv, m, 64);
            int   oi = __shfl_xor(bi, m, 64);
            if (ov > bv || (ov == bv && oi < bi)) { bv = ov; bi = oi; }
        }
        if (m15 == 0) {
            int row = n0 + w * 16 + q * 4 + r;
            ind[row] = bi;
            out_ind[row] = (float)bi;
        }
    }
}

// ---------------- gather quantize, scatter stats, commit loss ----------------
__global__ __launch_bounds__(256) void scatter_kernel(const float* __restrict__ x,
                                                      const float* __restrict__ embed,
                                                      const int* __restrict__ ind,
                                                      float* __restrict__ out_q,
                                                      float* __restrict__ bins,
                                                      float* __restrict__ esum,
                                                      float* __restrict__ loss,
                                                      int pmask) {
    int tid = threadIdx.x;
    int row = blockIdx.x * 2 + (tid >> 7);
    int d   = tid & 127;
    int p   = blockIdx.x & pmask;
    int k   = ind[row];
    float q  = embed[(size_t)k * DIM + d];
    float xv = x[(size_t)row * DIM + d];
    out_q[(size_t)row * DIM + d] = q;
    if (d == 0) atomicAdd(&bins[p * KCODES + k], 1.0f);
    atomicAdd(&esum[(size_t)p * KCODES * DIM + (size_t)k * DIM + d], xv);
    float diff = q - xv;
    float s = diff * diff;
    #pragma unroll
    for (int off = 32; off > 0; off >>= 1) s += __shfl_down(s, off, 64);
    __shared__ float ls[4];
    if ((tid & 63) == 0) ls[tid >> 6] = s;
    __syncthreads();
    if (tid == 0) atomicAdd(loss, ls[0] + ls[1] + ls[2] + ls[3]);
}

// ---------------- cs_new + n_total ----------------
__global__ __launch_bounds__(256) void cs_kernel(const float* __restrict__ cluster_size,
                                                 const float* __restrict__ bins,
                                                 float* __restrict__ out_cs,
                                                 float* __restrict__ ntot,
                                                 int ncopy) {
    int k = blockIdx.x * 256 + threadIdx.x;
    float b = 0.f;
    for (int p = 0; p < ncopy; p++) b += bins[p * KCODES + k];
    float cs = cluster_size[k] * DECAYF + (1.0f - DECAYF) * b;
    out_cs[k] = cs;
    float s = cs;
    #pragma unroll
    for (int off = 32; off > 0; off >>= 1) s += __shfl_down(s, off, 64);
    __shared__ float ls[4];
    if ((threadIdx.x & 63) == 0) ls[threadIdx.x >> 6] = s;
    __syncthreads();
    if (threadIdx.x == 0) atomicAdd(ntot, ls[0] + ls[1] + ls[2] + ls[3]);
}

// ---------------- embed_normalized + commit_loss finalize ----------------
__global__ __launch_bounds__(128) void norm_kernel(const float* __restrict__ embed_avg,
                                                   const float* __restrict__ esum,
                                                   const float* __restrict__ out_cs,
                                                   const float* __restrict__ ntot,
                                                   const float* __restrict__ loss,
                                                   float* __restrict__ out_norm,
                                                   float* __restrict__ out_loss,
                                                   int ncopy) {
    int k = blockIdx.x;
    int d = threadIdx.x;
    float nt = *ntot;
    float cs = out_cs[k];
    float cluster = (cs + EPSF) / (nt + (float)KCODES * EPSF) * nt;
    size_t idx = (size_t)k * DIM + d;
    float es = 0.f;
    for (int p = 0; p < ncopy; p++) es += esum[(size_t)p * KCODES * DIM + idx];
    float ea = embed_avg[idx] * DECAYF + (1.0f - DECAYF) * es;
    out_norm[idx] = ea / cluster;
    if (k == 0 && d == 0) {
        *out_loss = COMMITW * (*loss) / (float)((size_t)NROWS * DIM);
    }
}

extern "C" void kernel_launch(void* const* d_in, const int* in_sizes, int n_in,
                              void* d_out, int out_size, void* d_ws, size_t ws_size,
                              hipStream_t stream) {
    const float* x            = (const float*)d_in[0];
    const float* embed        = (const float*)d_in[1];
    const float* cluster_size = (const float*)d_in[2];
    const float* embed_avg    = (const float*)d_in[3];

    float* out      = (float*)d_out;
    float* out_q    = out;                               // 4194304
    float* out_ind  = out + 4194304;                     // 32768
    float* out_loss = out_ind + 32768;                   // 1
    float* out_cs   = out_loss + 1;                      // 4096
    float* out_norm = out_cs + 4096;                     // 524288

    // workspace layout (bytes)
    char* ws = (char*)d_ws;
    short* ehi  = (short*)ws;                            // 1,048,576
    short* emid = (short*)(ws + 1048576);                // 1,048,576
    short* elo  = (short*)(ws + 2097152);                // 1,048,576
    float* e2h  = (float*)(ws + 3145728);                // 16,384
    int*   ind  = (int*)(ws + 3162112);                  // 131,072
    float* loss = (float*)(ws + 3293184);                // 4 (pad to 256)
    float* ntot = loss + 1;
    float* bins = (float*)(ws + 3293440);                // ncopy*16,384
    size_t need8 = 3293440ull + 8ull * (16384 + 2097152);
    int ncopy = (ws_size >= need8) ? 8 : 1;
    float* esum = (float*)(ws + 3293440 + (size_t)ncopy * 16384);

    // zero loss/ntot/pad + bins + esum (contiguous)
    hipMemsetAsync(ws + 3293184, 0,
                   256 + (size_t)ncopy * (16384 + 2097152), stream);

    split_kernel<<<KCODES * DIM / 256, 256, 0, stream>>>(embed, ehi, emid, elo);
    e2_kernel<<<KCODES * 64 / 256, 256, 0, stream>>>(embed, e2h);
    argmax_kernel<<<NROWS / 64, 256, 0, stream>>>(x, ehi, emid, elo, e2h, ind, out_ind);
    scatter_kernel<<<NROWS / 2, 256, 0, stream>>>(x, embed, ind, out_q,
                                                  bins, esum, loss, ncopy - 1);
    cs_kernel<<<KCODES / 256, 256, 0, stream>>>(cluster_size, bins, out_cs, ntot, ncopy);
    norm_kernel<<<KCODES, 128, 0, stream>>>(embed_avg, esum, out_cs, ntot, loss,
                                            out_norm, out_loss, ncopy);
}

// Round 4
// 483.648 us; speedup vs baseline: 5.2504x; 2.0315x over previous
//
#include <hip/hip_runtime.h>

#define NROWS 32768
#define DIM   128
#define KCODES 4096
#define DECAYF 0.8f
#define EPSF 1e-5f
#define COMMITW 0.25f

typedef _Float16 half8 __attribute__((ext_vector_type(8)));
typedef float float4v __attribute__((ext_vector_type(4)));

// ---------------- embed -> 2-way fp16 split planes ----------------
__global__ __launch_bounds__(256) void esplit_kernel(const float* __restrict__ embed,
                                                     _Float16* __restrict__ ehi,
                                                     _Float16* __restrict__ elo) {
    int gid = blockIdx.x * 256 + threadIdx.x;
    float f = embed[gid];
    _Float16 h = (_Float16)f;
    _Float16 l = (_Float16)(f - (float)h);
    ehi[gid] = h;
    elo[gid] = l;
}

// ---------------- e2h[k] = 0.5 * sum_d embed[k][d]^2 ----------------
__global__ __launch_bounds__(256) void e2_kernel(const float* __restrict__ embed,
                                                 float* __restrict__ e2h) {
    int gid = blockIdx.x * blockDim.x + threadIdx.x;
    int wave = gid >> 6, lane = gid & 63;
    if (wave >= KCODES) return;
    float2 v = ((const float2*)(embed + (size_t)wave * DIM))[lane];
    float s = v.x * v.x + v.y * v.y;
    #pragma unroll
    for (int off = 32; off > 0; off >>= 1) s += __shfl_down(s, off, 64);
    if (lane == 0) e2h[wave] = 0.5f * s;
}

// ---------------- MFMA argmax ----------------
// score = x.e - 0.5|e|^2 (argmax-equivalent to -dist). fp16 2-way split,
// 3 products (hh, lh, hl); dropped ll ~2^-22 -> below fp32-serial error.
// Block: 256 thr / 4 waves, 64 rows. Wave w: rows (w>>1)*32 + i*16 + m15,
// codes j in {(w&1)*2, (w&1)*2+1} per 64-code chunk. A frags register-
// resident (split in-kernel). B chunk (32 KB, 2 planes) staged to LDS via
// global_load_lds(16B), layout [plane][ks][q][code]x16B -> ds_read_b128
// 2-way bank aliasing only (free, m136). m97 2-barrier K-loop.
__global__ __launch_bounds__(256, 2) void argmax_kernel(const float* __restrict__ x,
                                                        const _Float16* __restrict__ ehi,
                                                        const _Float16* __restrict__ elo,
                                                        const float* __restrict__ e2h,
                                                        int* __restrict__ ind,
                                                        float* __restrict__ out_ind) {
    __shared__ _Float16 bs[16384];   // 32 KB staged B chunk
    __shared__ float rv[2][64];
    __shared__ int   ri[2][64];

    int tid = threadIdx.x;
    int lane = tid & 63;
    int w = tid >> 6;
    int m15 = lane & 15;
    int q = (lane >> 4) & 3;
    int n0 = blockIdx.x * 64;
    int rbase = (w >> 1) * 32;
    int jbase = (w & 1) * 2;

    // A frags: lane (m15,q) holds A[m=m15][k=q*8+j] -> x[row][ks*32+q*8..+7]
    half8 Ah[2][4], Al[2][4];
    #pragma unroll
    for (int i = 0; i < 2; ++i)
        #pragma unroll
        for (int ks = 0; ks < 4; ++ks) {
            const float* p = x + (size_t)(n0 + rbase + i * 16 + m15) * DIM + ks * 32 + q * 8;
            float4 a = *(const float4*)p;
            float4 b = *(const float4*)(p + 4);
            float f[8] = {a.x, a.y, a.z, a.w, b.x, b.y, b.z, b.w};
            half8 H, L;
            #pragma unroll
            for (int e = 0; e < 8; ++e) {
                _Float16 h = (_Float16)f[e];
                H[e] = h;
                L[e] = (_Float16)(f[e] - (float)h);
            }
            Ah[i][ks] = H;
            Al[i][ks] = L;
        }

    float best[2][4];
    int   bidx[2][4];
    #pragma unroll
    for (int i = 0; i < 2; ++i)
        #pragma unroll
        for (int r = 0; r < 4; ++r) { best[i][r] = -3.0e38f; bidx[i][r] = 0; }

    for (int chunk = 0; chunk < 64; ++chunk) {
        int c0 = chunk * 64;
        float e2c[2];
        e2c[0] = e2h[c0 + (jbase + 0) * 16 + m15];
        e2c[1] = e2h[c0 + (jbase + 1) * 16 + m15];

        __syncthreads();   // previous chunk's LDS readers done
        // stage this chunk: 32 slices of 1KB; slice s: plane=s>>4, ks=(s>>2)&3, q=s&3
        #pragma unroll
        for (int t = 0; t < 8; ++t) {
            int s = w * 8 + t;
            int pl = s >> 4;
            int ks = (s >> 2) & 3;
            int qq = s & 3;
            const _Float16* gp = (pl ? elo : ehi) +
                                 (size_t)(c0 + lane) * DIM + ks * 32 + qq * 8;
            __builtin_amdgcn_global_load_lds(
                (const __attribute__((address_space(1))) unsigned int*)gp,
                (__attribute__((address_space(3))) unsigned int*)&bs[s * 512],
                16, 0, 0);
        }
        __syncthreads();   // drain vmcnt -> chunk visible

        #pragma unroll
        for (int jj = 0; jj < 2; ++jj) {
            int j = jbase + jj;
            float4v acc0 = {0.f, 0.f, 0.f, 0.f};
            float4v acc1 = {0.f, 0.f, 0.f, 0.f};
            #pragma unroll
            for (int ks = 0; ks < 4; ++ks) {
                const half8 Bh = *(const half8*)&bs[(((0 + ks) * 4 + q) * 64 + j * 16 + m15) * 8];
                const half8 Bl = *(const half8*)&bs[(((4 + ks) * 4 + q) * 64 + j * 16 + m15) * 8];
                acc0 = __builtin_amdgcn_mfma_f32_16x16x32_f16(Ah[0][ks], Bh, acc0, 0, 0, 0);
                acc1 = __builtin_amdgcn_mfma_f32_16x16x32_f16(Ah[1][ks], Bh, acc1, 0, 0, 0);
                acc0 = __builtin_amdgcn_mfma_f32_16x16x32_f16(Al[0][ks], Bh, acc0, 0, 0, 0);
                acc1 = __builtin_amdgcn_mfma_f32_16x16x32_f16(Al[1][ks], Bh, acc1, 0, 0, 0);
                acc0 = __builtin_amdgcn_mfma_f32_16x16x32_f16(Ah[0][ks], Bl, acc0, 0, 0, 0);
                acc1 = __builtin_amdgcn_mfma_f32_16x16x32_f16(Ah[1][ks], Bl, acc1, 0, 0, 0);
            }
            // C layout: row = q*4 + r, col(code-within-tile) = m15
            int c = c0 + j * 16 + m15;
            float e2v = e2c[jj];
            #pragma unroll
            for (int r = 0; r < 4; ++r) {
                float s0 = acc0[r] - e2v;
                if (s0 > best[0][r]) { best[0][r] = s0; bidx[0][r] = c; }
                float s1 = acc1[r] - e2v;
                if (s1 > best[1][r]) { best[1][r] = s1; bidx[1][r] = c; }
            }
        }
    }

    // reduce across the 16 codes held per lane-group (m15), min index on ties
    #pragma unroll
    for (int i = 0; i < 2; ++i)
        #pragma unroll
        for (int r = 0; r < 4; ++r) {
            float bv = best[i][r];
            int   bi = bidx[i][r];
            #pragma unroll
            for (int m = 1; m <= 8; m <<= 1) {
                float ov = __shfl_xor(bv, m, 64);
                int   oi = __shfl_xor(bi, m, 64);
                if (ov > bv || (ov == bv && oi < bi)) { bv = ov; bi = oi; }
            }
            if (m15 == 0) {
                int rl = rbase + i * 16 + q * 4 + r;
                rv[w & 1][rl] = bv;
                ri[w & 1][rl] = bi;
            }
        }
    __syncthreads();
    if (tid < 64) {
        float v0 = rv[0][tid]; int i0 = ri[0][tid];
        float v1 = rv[1][tid]; int i1 = ri[1][tid];
        bool take1 = (v1 > v0) || (v1 == v0 && i1 < i0);
        int bi = take1 ? i1 : i0;
        ind[n0 + tid] = bi;
        out_ind[n0 + tid] = (float)bi;
    }
}

// ---------------- gather quantize, scatter stats, commit loss ----------------
__global__ __launch_bounds__(256) void scatter_kernel(const float* __restrict__ x,
                                                      const float* __restrict__ embed,
                                                      const int* __restrict__ ind,
                                                      float* __restrict__ out_q,
                                                      float* __restrict__ bins,
                                                      float* __restrict__ esum,
                                                      float* __restrict__ loss,
                                                      int pmask) {
    int tid = threadIdx.x;
    int row = blockIdx.x * 2 + (tid >> 7);
    int d   = tid & 127;
    int p   = blockIdx.x & pmask;
    int k   = ind[row];
    float q  = embed[(size_t)k * DIM + d];
    float xv = x[(size_t)row * DIM + d];
    out_q[(size_t)row * DIM + d] = q;
    if (d == 0) atomicAdd(&bins[p * KCODES + k], 1.0f);
    atomicAdd(&esum[(size_t)p * KCODES * DIM + (size_t)k * DIM + d], xv);
    float diff = q - xv;
    float s = diff * diff;
    #pragma unroll
    for (int off = 32; off > 0; off >>= 1) s += __shfl_down(s, off, 64);
    __shared__ float ls[4];
    if ((tid & 63) == 0) ls[tid >> 6] = s;
    __syncthreads();
    if (tid == 0) atomicAdd(loss, ls[0] + ls[1] + ls[2] + ls[3]);
}

// ---------------- cs_new + n_total ----------------
__global__ __launch_bounds__(256) void cs_kernel(const float* __restrict__ cluster_size,
                                                 const float* __restrict__ bins,
                                                 float* __restrict__ out_cs,
                                                 float* __restrict__ ntot,
                                                 int ncopy) {
    int k = blockIdx.x * 256 + threadIdx.x;
    float b = 0.f;
    for (int p = 0; p < ncopy; p++) b += bins[p * KCODES + k];
    float cs = cluster_size[k] * DECAYF + (1.0f - DECAYF) * b;
    out_cs[k] = cs;
    float s = cs;
    #pragma unroll
    for (int off = 32; off > 0; off >>= 1) s += __shfl_down(s, off, 64);
    __shared__ float ls[4];
    if ((threadIdx.x & 63) == 0) ls[threadIdx.x >> 6] = s;
    __syncthreads();
    if (threadIdx.x == 0) atomicAdd(ntot, ls[0] + ls[1] + ls[2] + ls[3]);
}

// ---------------- embed_normalized + commit_loss finalize ----------------
__global__ __launch_bounds__(128) void norm_kernel(const float* __restrict__ embed_avg,
                                                   const float* __restrict__ esum,
                                                   const float* __restrict__ out_cs,
                                                   const float* __restrict__ ntot,
                                                   const float* __restrict__ loss,
                                                   float* __restrict__ out_norm,
                                                   float* __restrict__ out_loss,
                                                   int ncopy) {
    int k = blockIdx.x;
    int d = threadIdx.x;
    float nt = *ntot;
    float cs = out_cs[k];
    float cluster = (cs + EPSF) / (nt + (float)KCODES * EPSF) * nt;
    size_t idx = (size_t)k * DIM + d;
    float es = 0.f;
    for (int p = 0; p < ncopy; p++) es += esum[(size_t)p * KCODES * DIM + idx];
    float ea = embed_avg[idx] * DECAYF + (1.0f - DECAYF) * es;
    out_norm[idx] = ea / cluster;
    if (k == 0 && d == 0) {
        *out_loss = COMMITW * (*loss) / (float)((size_t)NROWS * DIM);
    }
}

extern "C" void kernel_launch(void* const* d_in, const int* in_sizes, int n_in,
                              void* d_out, int out_size, void* d_ws, size_t ws_size,
                              hipStream_t stream) {
    const float* x            = (const float*)d_in[0];
    const float* embed        = (const float*)d_in[1];
    const float* cluster_size = (const float*)d_in[2];
    const float* embed_avg    = (const float*)d_in[3];

    float* out      = (float*)d_out;
    float* out_q    = out;                               // 4194304
    float* out_ind  = out + 4194304;                     // 32768
    float* out_loss = out_ind + 32768;                   // 1
    float* out_cs   = out_loss + 1;                      // 4096
    float* out_norm = out_cs + 4096;                     // 524288

    // workspace layout (bytes)
    char* ws = (char*)d_ws;
    _Float16* ehi = (_Float16*)ws;                       // 1,048,576
    _Float16* elo = (_Float16*)(ws + 1048576);           // 1,048,576
    float* e2h  = (float*)(ws + 2097152);                // 16,384
    int*   ind  = (int*)(ws + 2113536);                  // 131,072
    float* loss = (float*)(ws + 2244608);                // 4 (pad to 256)
    float* ntot = loss + 1;
    float* bins = (float*)(ws + 2244864);                // ncopy*16,384
    size_t need8 = 2244864ull + 8ull * (16384 + 2097152);
    int ncopy = (ws_size >= need8) ? 8 : 1;
    float* esum = (float*)(ws + 2244864 + (size_t)ncopy * 16384);

    // zero loss/ntot/pad + bins + esum (contiguous)
    hipMemsetAsync(ws + 2244608, 0,
                   256 + (size_t)ncopy * (16384 + 2097152), stream);

    esplit_kernel<<<KCODES * DIM / 256, 256, 0, stream>>>(embed, ehi, elo);
    e2_kernel<<<KCODES * 64 / 256, 256, 0, stream>>>(embed, e2h);
    argmax_kernel<<<NROWS / 64, 256, 0, stream>>>(x, ehi, elo, e2h, ind, out_ind);
    scatter_kernel<<<NROWS / 2, 256, 0, stream>>>(x, embed, ind, out_q,
                                                  bins, esum, loss, ncopy - 1);
    cs_kernel<<<KCODES / 256, 256, 0, stream>>>(cluster_size, bins, out_cs, ntot, ncopy);
    norm_kernel<<<KCODES, 128, 0, stream>>>(embed_avg, esum, out_cs, ntot, loss,
                                            out_norm, out_loss, ncopy);
}

// Round 5
// 418.809 us; speedup vs baseline: 6.0632x; 1.1548x over previous
//
#include <hip/hip_runtime.h>

#define NROWS 32768
#define DIM   128
#define KCODES 4096
#define DECAYF 0.8f
#define EPSF 1e-5f
#define COMMITW 0.25f

typedef _Float16 half8 __attribute__((ext_vector_type(8)));
typedef float float4v __attribute__((ext_vector_type(4)));

// ---------------- embed -> 2-way fp16 split planes ----------------
__global__ __launch_bounds__(256) void esplit_kernel(const float* __restrict__ embed,
                                                     _Float16* __restrict__ ehi,
                                                     _Float16* __restrict__ elo) {
    int gid = blockIdx.x * 256 + threadIdx.x;
    float f = embed[gid];
    _Float16 h = (_Float16)f;
    _Float16 l = (_Float16)(f - (float)h);
    ehi[gid] = h;
    elo[gid] = l;
}

// ---------------- e2h[k] = 0.5 * sum_d embed[k][d]^2 ----------------
__global__ __launch_bounds__(256) void e2_kernel(const float* __restrict__ embed,
                                                 float* __restrict__ e2h) {
    int gid = blockIdx.x * blockDim.x + threadIdx.x;
    int wave = gid >> 6, lane = gid & 63;
    if (wave >= KCODES) return;
    float2 v = ((const float2*)(embed + (size_t)wave * DIM))[lane];
    float s = v.x * v.x + v.y * v.y;
    #pragma unroll
    for (int off = 32; off > 0; off >>= 1) s += __shfl_down(s, off, 64);
    if (lane == 0) e2h[wave] = 0.5f * s;
}

// ---------------- MFMA argmax (unchanged from R4) ----------------
__global__ __launch_bounds__(256, 2) void argmax_kernel(const float* __restrict__ x,
                                                        const _Float16* __restrict__ ehi,
                                                        const _Float16* __restrict__ elo,
                                                        const float* __restrict__ e2h,
                                                        int* __restrict__ ind,
                                                        float* __restrict__ out_ind) {
    __shared__ _Float16 bs[16384];   // 32 KB staged B chunk
    __shared__ float rv[2][64];
    __shared__ int   ri[2][64];

    int tid = threadIdx.x;
    int lane = tid & 63;
    int w = tid >> 6;
    int m15 = lane & 15;
    int q = (lane >> 4) & 3;
    int n0 = blockIdx.x * 64;
    int rbase = (w >> 1) * 32;
    int jbase = (w & 1) * 2;

    half8 Ah[2][4], Al[2][4];
    #pragma unroll
    for (int i = 0; i < 2; ++i)
        #pragma unroll
        for (int ks = 0; ks < 4; ++ks) {
            const float* p = x + (size_t)(n0 + rbase + i * 16 + m15) * DIM + ks * 32 + q * 8;
            float4 a = *(const float4*)p;
            float4 b = *(const float4*)(p + 4);
            float f[8] = {a.x, a.y, a.z, a.w, b.x, b.y, b.z, b.w};
            half8 H, L;
            #pragma unroll
            for (int e = 0; e < 8; ++e) {
                _Float16 h = (_Float16)f[e];
                H[e] = h;
                L[e] = (_Float16)(f[e] - (float)h);
            }
            Ah[i][ks] = H;
            Al[i][ks] = L;
        }

    float best[2][4];
    int   bidx[2][4];
    #pragma unroll
    for (int i = 0; i < 2; ++i)
        #pragma unroll
        for (int r = 0; r < 4; ++r) { best[i][r] = -3.0e38f; bidx[i][r] = 0; }

    for (int chunk = 0; chunk < 64; ++chunk) {
        int c0 = chunk * 64;
        float e2c[2];
        e2c[0] = e2h[c0 + (jbase + 0) * 16 + m15];
        e2c[1] = e2h[c0 + (jbase + 1) * 16 + m15];

        __syncthreads();
        #pragma unroll
        for (int t = 0; t < 8; ++t) {
            int s = w * 8 + t;
            int pl = s >> 4;
            int ks = (s >> 2) & 3;
            int qq = s & 3;
            const _Float16* gp = (pl ? elo : ehi) +
                                 (size_t)(c0 + lane) * DIM + ks * 32 + qq * 8;
            __builtin_amdgcn_global_load_lds(
                (const __attribute__((address_space(1))) unsigned int*)gp,
                (__attribute__((address_space(3))) unsigned int*)&bs[s * 512],
                16, 0, 0);
        }
        __syncthreads();

        #pragma unroll
        for (int jj = 0; jj < 2; ++jj) {
            int j = jbase + jj;
            float4v acc0 = {0.f, 0.f, 0.f, 0.f};
            float4v acc1 = {0.f, 0.f, 0.f, 0.f};
            #pragma unroll
            for (int ks = 0; ks < 4; ++ks) {
                const half8 Bh = *(const half8*)&bs[(((0 + ks) * 4 + q) * 64 + j * 16 + m15) * 8];
                const half8 Bl = *(const half8*)&bs[(((4 + ks) * 4 + q) * 64 + j * 16 + m15) * 8];
                acc0 = __builtin_amdgcn_mfma_f32_16x16x32_f16(Ah[0][ks], Bh, acc0, 0, 0, 0);
                acc1 = __builtin_amdgcn_mfma_f32_16x16x32_f16(Ah[1][ks], Bh, acc1, 0, 0, 0);
                acc0 = __builtin_amdgcn_mfma_f32_16x16x32_f16(Al[0][ks], Bh, acc0, 0, 0, 0);
                acc1 = __builtin_amdgcn_mfma_f32_16x16x32_f16(Al[1][ks], Bh, acc1, 0, 0, 0);
                acc0 = __builtin_amdgcn_mfma_f32_16x16x32_f16(Ah[0][ks], Bl, acc0, 0, 0, 0);
                acc1 = __builtin_amdgcn_mfma_f32_16x16x32_f16(Ah[1][ks], Bl, acc1, 0, 0, 0);
            }
            int c = c0 + j * 16 + m15;
            float e2v = e2c[jj];
            #pragma unroll
            for (int r = 0; r < 4; ++r) {
                float s0 = acc0[r] - e2v;
                if (s0 > best[0][r]) { best[0][r] = s0; bidx[0][r] = c; }
                float s1 = acc1[r] - e2v;
                if (s1 > best[1][r]) { best[1][r] = s1; bidx[1][r] = c; }
            }
        }
    }

    #pragma unroll
    for (int i = 0; i < 2; ++i)
        #pragma unroll
        for (int r = 0; r < 4; ++r) {
            float bv = best[i][r];
            int   bi = bidx[i][r];
            #pragma unroll
            for (int m = 1; m <= 8; m <<= 1) {
                float ov = __shfl_xor(bv, m, 64);
                int   oi = __shfl_xor(bi, m, 64);
                if (ov > bv || (ov == bv && oi < bi)) { bv = ov; bi = oi; }
            }
            if (m15 == 0) {
                int rl = rbase + i * 16 + q * 4 + r;
                rv[w & 1][rl] = bv;
                ri[w & 1][rl] = bi;
            }
        }
    __syncthreads();
    if (tid < 64) {
        float v0 = rv[0][tid]; int i0 = ri[0][tid];
        float v1 = rv[1][tid]; int i1 = ri[1][tid];
        bool take1 = (v1 > v0) || (v1 == v0 && i1 < i0);
        int bi = take1 ? i1 : i0;
        ind[n0 + tid] = bi;
        out_ind[n0 + tid] = (float)bi;
    }
}

// ---------------- histogram of ind -> bins (int) ----------------
__global__ __launch_bounds__(256) void hist_kernel(const int* __restrict__ ind,
                                                   int* __restrict__ bins) {
    __shared__ int lh[KCODES];
    int tid = threadIdx.x;
    #pragma unroll
    for (int t = 0; t < KCODES / 256; ++t) lh[tid + t * 256] = 0;
    __syncthreads();
    int base = blockIdx.x * 512;
    atomicAdd(&lh[ind[base + tid]], 1);
    atomicAdd(&lh[ind[base + 256 + tid]], 1);
    __syncthreads();
    #pragma unroll
    for (int t = 0; t < KCODES / 256; ++t) {
        int v = lh[tid + t * 256];
        if (v) atomicAdd(&bins[tid + t * 256], v);
    }
}

// ---------------- scan: offsets/cursor + out_cs + ntot ----------------
__global__ __launch_bounds__(1024) void scan_kernel(const int* __restrict__ bins,
                                                    const float* __restrict__ cluster_size,
                                                    int* __restrict__ offsets,
                                                    int* __restrict__ cursor,
                                                    float* __restrict__ out_cs,
                                                    float* __restrict__ ntot) {
    __shared__ int sdata[1024];
    __shared__ float fred[1024];
    int t = threadIdx.x;
    int b[4];
    float cs[4];
    float csum = 0.f;
    int s = 0;
    #pragma unroll
    for (int e = 0; e < 4; ++e) {
        b[e] = bins[t * 4 + e];
        s += b[e];
        cs[e] = cluster_size[t * 4 + e] * DECAYF + (1.0f - DECAYF) * (float)b[e];
        csum += cs[e];
    }
    int mysum = s;
    sdata[t] = s;
    __syncthreads();
    for (int off = 1; off < 1024; off <<= 1) {
        int v = (t >= off) ? sdata[t - off] : 0;
        __syncthreads();
        sdata[t] += v;
        __syncthreads();
    }
    int ex = sdata[t] - mysum;
    #pragma unroll
    for (int e = 0; e < 4; ++e) {
        offsets[t * 4 + e] = ex;
        cursor[t * 4 + e] = ex;
        out_cs[t * 4 + e] = cs[e];
        ex += b[e];
    }
    // reduce csum -> ntot
    fred[t] = csum;
    __syncthreads();
    for (int off = 512; off > 0; off >>= 1) {
        if (t < off) fred[t] += fred[t + off];
        __syncthreads();
    }
    if (t == 0) *ntot = fred[0];
}

// ---------------- reorder rows by code ----------------
__global__ __launch_bounds__(256) void reorder_kernel(const int* __restrict__ ind,
                                                      int* __restrict__ cursor,
                                                      int* __restrict__ rowids) {
    int row = blockIdx.x * 256 + threadIdx.x;
    int k = ind[row];
    int pos = atomicAdd(&cursor[k], 1);
    rowids[pos] = row;
}

// ---------------- gather out_q + commit loss (streaming, few atomics) ------
__global__ __launch_bounds__(256) void gather_kernel(const float* __restrict__ x,
                                                     const float* __restrict__ embed,
                                                     const int* __restrict__ ind,
                                                     float* __restrict__ out_q,
                                                     float* __restrict__ loss) {
    int tid = threadIdx.x;
    int d = tid & 127;
    float acc = 0.f;
    #pragma unroll 4
    for (int p = 0; p < 16; ++p) {
        int row = blockIdx.x * 32 + p * 2 + (tid >> 7);
        int k = ind[row];
        float q  = embed[(size_t)k * DIM + d];
        float xv = x[(size_t)row * DIM + d];
        out_q[(size_t)row * DIM + d] = q;
        float diff = q - xv;
        acc += diff * diff;
    }
    #pragma unroll
    for (int off = 32; off > 0; off >>= 1) acc += __shfl_down(acc, off, 64);
    __shared__ float ls[4];
    if ((tid & 63) == 0) ls[tid >> 6] = acc;
    __syncthreads();
    if (tid == 0) atomicAdd(loss, ls[0] + ls[1] + ls[2] + ls[3]);
}

// ---------------- segmented esum + norm (one wave per code) ----------------
__global__ __launch_bounds__(256) void esum_norm_kernel(const float* __restrict__ x,
                                                        const int* __restrict__ offsets,
                                                        const int* __restrict__ bins,
                                                        const int* __restrict__ rowids,
                                                        const float* __restrict__ embed_avg,
                                                        const float* __restrict__ out_cs,
                                                        const float* __restrict__ ntot,
                                                        const float* __restrict__ loss,
                                                        float* __restrict__ out_norm,
                                                        float* __restrict__ out_loss) {
    int tid = threadIdx.x;
    int lane = tid & 63;
    int k = blockIdx.x * 4 + (tid >> 6);
    int beg = offsets[k];
    int cnt = bins[k];
    float2 acc = {0.f, 0.f};
    for (int i = 0; i < cnt; ++i) {
        int row = rowids[beg + i];
        float2 v = ((const float2*)(x + (size_t)row * DIM))[lane];
        acc.x += v.x;
        acc.y += v.y;
    }
    float nt = *ntot;
    float cs = out_cs[k];
    float cluster = (cs + EPSF) / (nt + (float)KCODES * EPSF) * nt;
    float inv = 1.0f / cluster;
    size_t idx = (size_t)k * DIM + lane * 2;
    float2 ea = *(const float2*)(embed_avg + idx);
    float2 o;
    o.x = (ea.x * DECAYF + (1.0f - DECAYF) * acc.x) * inv;
    o.y = (ea.y * DECAYF + (1.0f - DECAYF) * acc.y) * inv;
    *(float2*)(out_norm + idx) = o;
    if (k == 0 && lane == 0) {
        *out_loss = COMMITW * (*loss) / (float)((size_t)NROWS * DIM);
    }
}

extern "C" void kernel_launch(void* const* d_in, const int* in_sizes, int n_in,
                              void* d_out, int out_size, void* d_ws, size_t ws_size,
                              hipStream_t stream) {
    const float* x            = (const float*)d_in[0];
    const float* embed        = (const float*)d_in[1];
    const float* cluster_size = (const float*)d_in[2];
    const float* embed_avg    = (const float*)d_in[3];

    float* out      = (float*)d_out;
    float* out_q    = out;                               // 4194304
    float* out_ind  = out + 4194304;                     // 32768
    float* out_loss = out_ind + 32768;                   // 1
    float* out_cs   = out_loss + 1;                      // 4096
    float* out_norm = out_cs + 4096;                     // 524288

    // workspace layout (bytes)
    char* ws = (char*)d_ws;
    _Float16* ehi = (_Float16*)ws;                       // 1,048,576
    _Float16* elo = (_Float16*)(ws + 1048576);           // 1,048,576
    float* e2h   = (float*)(ws + 2097152);               // 16,384
    int*   ind   = (int*)(ws + 2113536);                 // 131,072
    float* loss  = (float*)(ws + 2244608);               // 4
    float* ntot  = loss + 1;                             // 4 (pad to 256)
    int*   bins  = (int*)(ws + 2244864);                 // 16,384
    int*   offsets = (int*)(ws + 2261248);               // 16,384
    int*   cursor  = (int*)(ws + 2277632);               // 16,384
    int*   rowids  = (int*)(ws + 2294016);               // 131,072

    // zero loss/ntot/pad + bins (contiguous, 16.6 KB)
    hipMemsetAsync(ws + 2244608, 0, 256 + 16384, stream);

    esplit_kernel<<<KCODES * DIM / 256, 256, 0, stream>>>(embed, ehi, elo);
    e2_kernel<<<KCODES * 64 / 256, 256, 0, stream>>>(embed, e2h);
    argmax_kernel<<<NROWS / 64, 256, 0, stream>>>(x, ehi, elo, e2h, ind, out_ind);
    hist_kernel<<<NROWS / 512, 256, 0, stream>>>(ind, bins);
    scan_kernel<<<1, 1024, 0, stream>>>(bins, cluster_size, offsets, cursor,
                                        out_cs, ntot);
    reorder_kernel<<<NROWS / 256, 256, 0, stream>>>(ind, cursor, rowids);
    gather_kernel<<<NROWS / 32, 256, 0, stream>>>(x, embed, ind, out_q, loss);
    esum_norm_kernel<<<KCODES / 4, 256, 0, stream>>>(x, offsets, bins, rowids,
                                                     embed_avg, out_cs, ntot, loss,
                                                     out_norm, out_loss);
}

// Round 6
// 407.542 us; speedup vs baseline: 6.2308x; 1.0276x over previous
//
#include <hip/hip_runtime.h>

#define NROWS 32768
#define DIM   128
#define KCODES 4096
#define DECAYF 0.8f
#define EPSF 1e-5f
#define COMMITW 0.25f

typedef _Float16 half8 __attribute__((ext_vector_type(8)));
typedef float float4v __attribute__((ext_vector_type(4)));

// ---------------- embed -> 2-way fp16 split planes ----------------
__global__ __launch_bounds__(256) void esplit_kernel(const float* __restrict__ embed,
                                                     _Float16* __restrict__ ehi,
                                                     _Float16* __restrict__ elo) {
    int gid = blockIdx.x * 256 + threadIdx.x;
    float f = embed[gid];
    _Float16 h = (_Float16)f;
    _Float16 l = (_Float16)(f - (float)h);
    ehi[gid] = h;
    elo[gid] = l;
}

// ---------------- e2h[k] = 0.5 * sum_d embed[k][d]^2 ----------------
__global__ __launch_bounds__(256) void e2_kernel(const float* __restrict__ embed,
                                                 float* __restrict__ e2h) {
    int gid = blockIdx.x * blockDim.x + threadIdx.x;
    int wave = gid >> 6, lane = gid & 63;
    if (wave >= KCODES) return;
    float2 v = ((const float2*)(embed + (size_t)wave * DIM))[lane];
    float s = v.x * v.x + v.y * v.y;
    #pragma unroll
    for (int off = 32; off > 0; off >>= 1) s += __shfl_down(s, off, 64);
    if (lane == 0) e2h[wave] = 0.5f * s;
}

// ---------------- MFMA argmax, A-register-resident ----------------
// score = x.e - 0.5|e|^2. fp16 2-way split, 3 products (hh, lh, hl).
// Block: 4 waves, 64 rows. Every wave holds ALL 64 rows' A-frags resident
// (4 row-tiles x 4 ks x 2 planes = 128 VGPRs). Waves split each staged
// 64-code chunk: wave w takes code-tile j=w. Per chunk/wave: 8 ds_read_b128
// -> 48 MFMAs (1:6). Also emits bins histogram (64 atomics/block) and the
// commit-loss partial via |x|^2 - 2*best (score identity).
__global__ __launch_bounds__(256, 2) void argmax_kernel(const float* __restrict__ x,
                                                        const _Float16* __restrict__ ehi,
                                                        const _Float16* __restrict__ elo,
                                                        const float* __restrict__ e2h,
                                                        int* __restrict__ ind,
                                                        float* __restrict__ out_ind,
                                                        int* __restrict__ bins,
                                                        float* __restrict__ loss) {
    __shared__ _Float16 bs[16384];   // 32 KB staged B chunk
    __shared__ float rv[4][64];
    __shared__ int   ri[4][64];
    __shared__ float x2s[64];

    int tid = threadIdx.x;
    int lane = tid & 63;
    int w = tid >> 6;
    int m15 = lane & 15;
    int q = (lane >> 4) & 3;
    int n0 = blockIdx.x * 64;

    // A frags for all 64 rows, resident; also per-row |x|^2 (fp32 exact)
    half8 Ah[4][4], Al[4][4];
    float xsq[4];
    #pragma unroll
    for (int rt = 0; rt < 4; ++rt) {
        xsq[rt] = 0.f;
        #pragma unroll
        for (int ks = 0; ks < 4; ++ks) {
            const float* p = x + (size_t)(n0 + rt * 16 + m15) * DIM + ks * 32 + q * 8;
            float4 a = *(const float4*)p;
            float4 b = *(const float4*)(p + 4);
            float f[8] = {a.x, a.y, a.z, a.w, b.x, b.y, b.z, b.w};
            half8 H, L;
            #pragma unroll
            for (int e = 0; e < 8; ++e) {
                _Float16 h = (_Float16)f[e];
                H[e] = h;
                L[e] = (_Float16)(f[e] - (float)h);
                xsq[rt] += f[e] * f[e];
            }
            Ah[rt][ks] = H;
            Al[rt][ks] = L;
        }
        // reduce |x|^2 over the 4 q-lanes sharing this row
        xsq[rt] += __shfl_xor(xsq[rt], 16, 64);
        xsq[rt] += __shfl_xor(xsq[rt], 32, 64);
    }
    if (w == 0 && lane < 16) {
        #pragma unroll
        for (int rt = 0; rt < 4; ++rt) x2s[rt * 16 + m15] = xsq[rt];
    }

    float best[4][4];
    int   bidx[4][4];
    #pragma unroll
    for (int rt = 0; rt < 4; ++rt)
        #pragma unroll
        for (int r = 0; r < 4; ++r) { best[rt][r] = -3.0e38f; bidx[rt][r] = 0; }

    for (int chunk = 0; chunk < 64; ++chunk) {
        int c0 = chunk * 64;
        float e2v = e2h[c0 + w * 16 + m15];

        __syncthreads();   // previous chunk's LDS readers done
        #pragma unroll
        for (int t = 0; t < 8; ++t) {
            int s = w * 8 + t;
            int pl = s >> 4;
            int ks = (s >> 2) & 3;
            int qq = s & 3;
            const _Float16* gp = (pl ? elo : ehi) +
                                 (size_t)(c0 + lane) * DIM + ks * 32 + qq * 8;
            __builtin_amdgcn_global_load_lds(
                (const __attribute__((address_space(1))) unsigned int*)gp,
                (__attribute__((address_space(3))) unsigned int*)&bs[s * 512],
                16, 0, 0);
        }
        __syncthreads();   // drain -> chunk visible

        float4v acc[4];
        #pragma unroll
        for (int rt = 0; rt < 4; ++rt) acc[rt] = (float4v){0.f, 0.f, 0.f, 0.f};

        #pragma unroll
        for (int ks = 0; ks < 4; ++ks) {
            const half8 Bh = *(const half8*)&bs[(((0 + ks) * 4 + q) * 64 + w * 16 + m15) * 8];
            const half8 Bl = *(const half8*)&bs[(((4 + ks) * 4 + q) * 64 + w * 16 + m15) * 8];
            #pragma unroll
            for (int rt = 0; rt < 4; ++rt) {
                acc[rt] = __builtin_amdgcn_mfma_f32_16x16x32_f16(Ah[rt][ks], Bh, acc[rt], 0, 0, 0);
                acc[rt] = __builtin_amdgcn_mfma_f32_16x16x32_f16(Al[rt][ks], Bh, acc[rt], 0, 0, 0);
                acc[rt] = __builtin_amdgcn_mfma_f32_16x16x32_f16(Ah[rt][ks], Bl, acc[rt], 0, 0, 0);
            }
        }

        // C layout: row-within-tile = q*4+r, col(code) = m15.
        // codes ascend with chunk -> strict > keeps lowest index on ties
        int c = c0 + w * 16 + m15;
        #pragma unroll
        for (int rt = 0; rt < 4; ++rt)
            #pragma unroll
            for (int r = 0; r < 4; ++r) {
                float s = acc[rt][r] - e2v;
                if (s > best[rt][r]) { best[rt][r] = s; bidx[rt][r] = c; }
            }
    }

    // reduce across the 16 code-lanes (m15); min index on ties
    #pragma unroll
    for (int rt = 0; rt < 4; ++rt)
        #pragma unroll
        for (int r = 0; r < 4; ++r) {
            float bv = best[rt][r];
            int   bi = bidx[rt][r];
            #pragma unroll
            for (int m = 1; m <= 8; m <<= 1) {
                float ov = __shfl_xor(bv, m, 64);
                int   oi = __shfl_xor(bi, m, 64);
                if (ov > bv || (ov == bv && oi < bi)) { bv = ov; bi = oi; }
            }
            if (m15 == 0) {
                int rl = rt * 16 + q * 4 + r;
                rv[w][rl] = bv;
                ri[w][rl] = bi;
            }
        }
    __syncthreads();
    if (tid < 64) {
        float bv = rv[0][tid];
        int   bi = ri[0][tid];
        #pragma unroll
        for (int ww = 1; ww < 4; ++ww) {
            float ov = rv[ww][tid];
            int   oi = ri[ww][tid];
            if (ov > bv || (ov == bv && oi < bi)) { bv = ov; bi = oi; }
        }
        ind[n0 + tid] = bi;
        out_ind[n0 + tid] = (float)bi;
        atomicAdd(&bins[bi], 1);
        // commit-loss partial: |x - e_k|^2 = |x|^2 - 2*best_score
        float lp = x2s[tid] - 2.0f * bv;
        #pragma unroll
        for (int off = 32; off > 0; off >>= 1) lp += __shfl_down(lp, off, 64);
        if (tid == 0) atomicAdd(loss, lp);
    }
}

// ---------------- scan: offsets/cursor + out_cs + ntot + out_loss ----------
__global__ __launch_bounds__(1024) void scan_kernel(const int* __restrict__ bins,
                                                    const float* __restrict__ cluster_size,
                                                    const float* __restrict__ loss,
                                                    int* __restrict__ offsets,
                                                    int* __restrict__ cursor,
                                                    float* __restrict__ out_cs,
                                                    float* __restrict__ ntot,
                                                    float* __restrict__ out_loss) {
    __shared__ int sdata[1024];
    __shared__ float fred[1024];
    int t = threadIdx.x;
    int b[4];
    float cs[4];
    float csum = 0.f;
    int s = 0;
    #pragma unroll
    for (int e = 0; e < 4; ++e) {
        b[e] = bins[t * 4 + e];
        s += b[e];
        cs[e] = cluster_size[t * 4 + e] * DECAYF + (1.0f - DECAYF) * (float)b[e];
        csum += cs[e];
    }
    int mysum = s;
    sdata[t] = s;
    __syncthreads();
    for (int off = 1; off < 1024; off <<= 1) {
        int v = (t >= off) ? sdata[t - off] : 0;
        __syncthreads();
        sdata[t] += v;
        __syncthreads();
    }
    int ex = sdata[t] - mysum;
    #pragma unroll
    for (int e = 0; e < 4; ++e) {
        offsets[t * 4 + e] = ex;
        cursor[t * 4 + e] = ex;
        out_cs[t * 4 + e] = cs[e];
        ex += b[e];
    }
    fred[t] = csum;
    __syncthreads();
    for (int off = 512; off > 0; off >>= 1) {
        if (t < off) fred[t] += fred[t + off];
        __syncthreads();
    }
    if (t == 0) {
        *ntot = fred[0];
        *out_loss = COMMITW * (*loss) / (float)((size_t)NROWS * DIM);
    }
}

// ---------------- reorder rows by code ----------------
__global__ __launch_bounds__(256) void reorder_kernel(const int* __restrict__ ind,
                                                      int* __restrict__ cursor,
                                                      int* __restrict__ rowids) {
    int row = blockIdx.x * 256 + threadIdx.x;
    int k = ind[row];
    int pos = atomicAdd(&cursor[k], 1);
    rowids[pos] = row;
}

// ---------------- segmented esum + norm + out_q (one wave per code) --------
__global__ __launch_bounds__(256) void esum_norm_kernel(const float* __restrict__ x,
                                                        const float* __restrict__ embed,
                                                        const int* __restrict__ offsets,
                                                        const int* __restrict__ bins,
                                                        const int* __restrict__ rowids,
                                                        const float* __restrict__ embed_avg,
                                                        const float* __restrict__ out_cs,
                                                        const float* __restrict__ ntot,
                                                        float* __restrict__ out_q,
                                                        float* __restrict__ out_norm) {
    int tid = threadIdx.x;
    int lane = tid & 63;
    int k = blockIdx.x * 4 + (tid >> 6);
    int beg = offsets[k];
    int cnt = bins[k];
    float2 qv = ((const float2*)(embed + (size_t)k * DIM))[lane];
    float2 acc = {0.f, 0.f};
    for (int i = 0; i < cnt; ++i) {
        int row = rowids[beg + i];
        float2 v = ((const float2*)(x + (size_t)row * DIM))[lane];
        acc.x += v.x;
        acc.y += v.y;
        ((float2*)(out_q + (size_t)row * DIM))[lane] = qv;
    }
    float nt = *ntot;
    float cs = out_cs[k];
    float cluster = (cs + EPSF) / (nt + (float)KCODES * EPSF) * nt;
    float inv = 1.0f / cluster;
    size_t idx = (size_t)k * DIM + lane * 2;
    float2 ea = *(const float2*)(embed_avg + idx);
    float2 o;
    o.x = (ea.x * DECAYF + (1.0f - DECAYF) * acc.x) * inv;
    o.y = (ea.y * DECAYF + (1.0f - DECAYF) * acc.y) * inv;
    *(float2*)(out_norm + idx) = o;
}

extern "C" void kernel_launch(void* const* d_in, const int* in_sizes, int n_in,
                              void* d_out, int out_size, void* d_ws, size_t ws_size,
                              hipStream_t stream) {
    const float* x            = (const float*)d_in[0];
    const float* embed        = (const float*)d_in[1];
    const float* cluster_size = (const float*)d_in[2];
    const float* embed_avg    = (const float*)d_in[3];

    float* out      = (float*)d_out;
    float* out_q    = out;                               // 4194304
    float* out_ind  = out + 4194304;                     // 32768
    float* out_loss = out_ind + 32768;                   // 1
    float* out_cs   = out_loss + 1;                      // 4096
    float* out_norm = out_cs + 4096;                     // 524288

    // workspace layout (bytes)
    char* ws = (char*)d_ws;
    _Float16* ehi = (_Float16*)ws;                       // 1,048,576
    _Float16* elo = (_Float16*)(ws + 1048576);           // 1,048,576
    float* e2h   = (float*)(ws + 2097152);               // 16,384
    int*   ind   = (int*)(ws + 2113536);                 // 131,072
    float* loss  = (float*)(ws + 2244608);               // 4 (pad to 256)
    float* ntot  = loss + 1;
    int*   bins  = (int*)(ws + 2244864);                 // 16,384
    int*   offsets = (int*)(ws + 2261248);               // 16,384
    int*   cursor  = (int*)(ws + 2277632);               // 16,384
    int*   rowids  = (int*)(ws + 2294016);               // 131,072

    // zero loss/pad + bins (contiguous, 16.6 KB)
    hipMemsetAsync(ws + 2244608, 0, 256 + 16384, stream);

    esplit_kernel<<<KCODES * DIM / 256, 256, 0, stream>>>(embed, ehi, elo);
    e2_kernel<<<KCODES * 64 / 256, 256, 0, stream>>>(embed, e2h);
    argmax_kernel<<<NROWS / 64, 256, 0, stream>>>(x, ehi, elo, e2h, ind, out_ind,
                                                  bins, loss);
    scan_kernel<<<1, 1024, 0, stream>>>(bins, cluster_size, loss, offsets, cursor,
                                        out_cs, ntot, out_loss);
    reorder_kernel<<<NROWS / 256, 256, 0, stream>>>(ind, cursor, rowids);
    esum_norm_kernel<<<KCODES / 4, 256, 0, stream>>>(x, embed, offsets, bins, rowids,
                                                     embed_avg, out_cs, ntot,
                                                     out_q, out_norm);
}

// Round 7
// 332.261 us; speedup vs baseline: 7.6426x; 1.2266x over previous
//
#include <hip/hip_runtime.h>

#define NROWS 32768
#define DIM   128
#define KCODES 4096
#define DECAYF 0.8f
#define EPSF 1e-5f
#define COMMITW 0.25f

typedef _Float16 half8 __attribute__((ext_vector_type(8)));
typedef _Float16 half2v __attribute__((ext_vector_type(2)));
typedef float float4v __attribute__((ext_vector_type(4)));

// ---------------- embed -> staged split planes + e2 ----------------
// estg layout (halves): [chunk][slice][code6][8] where slice = pl*16 + ks*4 + q
// (32 slices/chunk, 512 halves each = 1 KB contiguous -> coalesced wave loads).
// One wave per code row; also emits e2h[k] = 0.5*|e_k|^2.
__global__ __launch_bounds__(256) void esplit_kernel(const float* __restrict__ embed,
                                                     _Float16* __restrict__ estg,
                                                     float* __restrict__ e2h) {
    int code = blockIdx.x * 4 + (threadIdx.x >> 6);
    int lane = threadIdx.x & 63;
    float2 v = ((const float2*)(embed + (size_t)code * DIM))[lane];
    float s = v.x * v.x + v.y * v.y;
    #pragma unroll
    for (int off = 32; off > 0; off >>= 1) s += __shfl_down(s, off, 64);
    if (lane == 0) e2h[code] = 0.5f * s;

    int d = lane * 2;
    int ks = d >> 5, q = (d >> 3) & 3, j = d & 7;
    _Float16 h0 = (_Float16)v.x, l0 = (_Float16)(v.x - (float)h0);
    _Float16 h1 = (_Float16)v.y, l1 = (_Float16)(v.y - (float)h1);
    int chunk = code >> 6, c6 = code & 63;
    size_t base = (size_t)chunk * 16384;
    size_t hidx = base + (size_t)(( 0 + ks * 4 + q) * 64 + c6) * 8 + j;
    size_t lidx = base + (size_t)((16 + ks * 4 + q) * 64 + c6) * 8 + j;
    *(half2v*)&estg[hidx] = (half2v){h0, h1};
    *(half2v*)&estg[lidx] = (half2v){l0, l1};
}

// ---------------- MFMA argmax, A-register-resident, coalesced staging ------
// score = x.e - 0.5|e|^2. fp16 2-way split, 3 products (hh, lh, hl).
// Block: 4 waves, 64 rows; every wave holds all 64 rows' A-frags resident.
// Waves split each staged 64-code chunk (wave w takes code-tile j=w).
// Staging: 32 slices x 1 KB contiguous from estg -> global_load_lds(16B)
// fully coalesced. Per chunk/wave: 8 ds_read_b128 -> 48 MFMAs.
// Also emits bins histogram + commit-loss partial (|x|^2 - 2*best).
__global__ __launch_bounds__(256, 2) void argmax_kernel(const float* __restrict__ x,
                                                        const _Float16* __restrict__ estg,
                                                        const float* __restrict__ e2h,
                                                        int* __restrict__ ind,
                                                        float* __restrict__ out_ind,
                                                        int* __restrict__ bins,
                                                        float* __restrict__ loss) {
    __shared__ _Float16 bs[16384];   // 32 KB staged B chunk
    __shared__ float rv[4][64];
    __shared__ int   ri[4][64];
    __shared__ float x2s[64];

    int tid = threadIdx.x;
    int lane = tid & 63;
    int w = tid >> 6;
    int m15 = lane & 15;
    int q = (lane >> 4) & 3;
    int n0 = blockIdx.x * 64;

    // A frags for all 64 rows, resident; also per-row |x|^2 (fp32 exact)
    half8 Ah[4][4], Al[4][4];
    float xsq[4];
    #pragma unroll
    for (int rt = 0; rt < 4; ++rt) {
        xsq[rt] = 0.f;
        #pragma unroll
        for (int ks = 0; ks < 4; ++ks) {
            const float* p = x + (size_t)(n0 + rt * 16 + m15) * DIM + ks * 32 + q * 8;
            float4 a = *(const float4*)p;
            float4 b = *(const float4*)(p + 4);
            float f[8] = {a.x, a.y, a.z, a.w, b.x, b.y, b.z, b.w};
            half8 H, L;
            #pragma unroll
            for (int e = 0; e < 8; ++e) {
                _Float16 h = (_Float16)f[e];
                H[e] = h;
                L[e] = (_Float16)(f[e] - (float)h);
                xsq[rt] += f[e] * f[e];
            }
            Ah[rt][ks] = H;
            Al[rt][ks] = L;
        }
        xsq[rt] += __shfl_xor(xsq[rt], 16, 64);
        xsq[rt] += __shfl_xor(xsq[rt], 32, 64);
    }
    if (w == 0 && lane < 16) {
        #pragma unroll
        for (int rt = 0; rt < 4; ++rt) x2s[rt * 16 + m15] = xsq[rt];
    }

    float best[4][4];
    int   bidx[4][4];
    #pragma unroll
    for (int rt = 0; rt < 4; ++rt)
        #pragma unroll
        for (int r = 0; r < 4; ++r) { best[rt][r] = -3.0e38f; bidx[rt][r] = 0; }

    for (int chunk = 0; chunk < 64; ++chunk) {
        int c0 = chunk * 64;
        float e2v = e2h[c0 + w * 16 + m15];

        __syncthreads();   // previous chunk's LDS readers done
        #pragma unroll
        for (int t = 0; t < 8; ++t) {
            int s = w * 8 + t;
            const _Float16* gp = estg + (size_t)chunk * 16384 + s * 512 + lane * 8;
            __builtin_amdgcn_global_load_lds(
                (const __attribute__((address_space(1))) unsigned int*)gp,
                (__attribute__((address_space(3))) unsigned int*)&bs[s * 512],
                16, 0, 0);
        }
        __syncthreads();   // drain -> chunk visible

        float4v acc[4];
        #pragma unroll
        for (int rt = 0; rt < 4; ++rt) acc[rt] = (float4v){0.f, 0.f, 0.f, 0.f};

        #pragma unroll
        for (int ks = 0; ks < 4; ++ks) {
            const half8 Bh = *(const half8*)&bs[(((0 + ks) * 4 + q) * 64 + w * 16 + m15) * 8];
            const half8 Bl = *(const half8*)&bs[(((4 + ks) * 4 + q) * 64 + w * 16 + m15) * 8];
            #pragma unroll
            for (int rt = 0; rt < 4; ++rt) {
                acc[rt] = __builtin_amdgcn_mfma_f32_16x16x32_f16(Ah[rt][ks], Bh, acc[rt], 0, 0, 0);
                acc[rt] = __builtin_amdgcn_mfma_f32_16x16x32_f16(Al[rt][ks], Bh, acc[rt], 0, 0, 0);
                acc[rt] = __builtin_amdgcn_mfma_f32_16x16x32_f16(Ah[rt][ks], Bl, acc[rt], 0, 0, 0);
            }
        }

        // C layout: row-within-tile = q*4+r, col(code) = m15.
        int c = c0 + w * 16 + m15;
        #pragma unroll
        for (int rt = 0; rt < 4; ++rt)
            #pragma unroll
            for (int r = 0; r < 4; ++r) {
                float s = acc[rt][r] - e2v;
                if (s > best[rt][r]) { best[rt][r] = s; bidx[rt][r] = c; }
            }
    }

    // reduce across the 16 code-lanes (m15); min index on ties
    #pragma unroll
    for (int rt = 0; rt < 4; ++rt)
        #pragma unroll
        for (int r = 0; r < 4; ++r) {
            float bv = best[rt][r];
            int   bi = bidx[rt][r];
            #pragma unroll
            for (int m = 1; m <= 8; m <<= 1) {
                float ov = __shfl_xor(bv, m, 64);
                int   oi = __shfl_xor(bi, m, 64);
                if (ov > bv || (ov == bv && oi < bi)) { bv = ov; bi = oi; }
            }
            if (m15 == 0) {
                int rl = rt * 16 + q * 4 + r;
                rv[w][rl] = bv;
                ri[w][rl] = bi;
            }
        }
    __syncthreads();
    if (tid < 64) {
        float bv = rv[0][tid];
        int   bi = ri[0][tid];
        #pragma unroll
        for (int ww = 1; ww < 4; ++ww) {
            float ov = rv[ww][tid];
            int   oi = ri[ww][tid];
            if (ov > bv || (ov == bv && oi < bi)) { bv = ov; bi = oi; }
        }
        ind[n0 + tid] = bi;
        out_ind[n0 + tid] = (float)bi;
        atomicAdd(&bins[bi], 1);
        float lp = x2s[tid] - 2.0f * bv;
        #pragma unroll
        for (int off = 32; off > 0; off >>= 1) lp += __shfl_down(lp, off, 64);
        if (tid == 0) atomicAdd(loss, lp);
    }
}

// ---------------- scan: offsets/cursor + out_cs + ntot + out_loss ----------
__global__ __launch_bounds__(1024) void scan_kernel(const int* __restrict__ bins,
                                                    const float* __restrict__ cluster_size,
                                                    const float* __restrict__ loss,
                                                    int* __restrict__ offsets,
                                                    int* __restrict__ cursor,
                                                    float* __restrict__ out_cs,
                                                    float* __restrict__ ntot,
                                                    float* __restrict__ out_loss) {
    __shared__ int sdata[1024];
    __shared__ float fred[1024];
    int t = threadIdx.x;
    int b[4];
    float cs[4];
    float csum = 0.f;
    int s = 0;
    #pragma unroll
    for (int e = 0; e < 4; ++e) {
        b[e] = bins[t * 4 + e];
        s += b[e];
        cs[e] = cluster_size[t * 4 + e] * DECAYF + (1.0f - DECAYF) * (float)b[e];
        csum += cs[e];
    }
    int mysum = s;
    sdata[t] = s;
    __syncthreads();
    for (int off = 1; off < 1024; off <<= 1) {
        int v = (t >= off) ? sdata[t - off] : 0;
        __syncthreads();
        sdata[t] += v;
        __syncthreads();
    }
    int ex = sdata[t] - mysum;
    #pragma unroll
    for (int e = 0; e < 4; ++e) {
        offsets[t * 4 + e] = ex;
        cursor[t * 4 + e] = ex;
        out_cs[t * 4 + e] = cs[e];
        ex += b[e];
    }
    fred[t] = csum;
    __syncthreads();
    for (int off = 512; off > 0; off >>= 1) {
        if (t < off) fred[t] += fred[t + off];
        __syncthreads();
    }
    if (t == 0) {
        *ntot = fred[0];
        *out_loss = COMMITW * (*loss) / (float)((size_t)NROWS * DIM);
    }
}

// ---------------- reorder rows by code ----------------
__global__ __launch_bounds__(256) void reorder_kernel(const int* __restrict__ ind,
                                                      int* __restrict__ cursor,
                                                      int* __restrict__ rowids) {
    int row = blockIdx.x * 256 + threadIdx.x;
    int k = ind[row];
    int pos = atomicAdd(&cursor[k], 1);
    rowids[pos] = row;
}

// ---------------- segmented esum + norm + out_q (one wave per code) --------
__global__ __launch_bounds__(256) void esum_norm_kernel(const float* __restrict__ x,
                                                        const float* __restrict__ embed,
                                                        const int* __restrict__ offsets,
                                                        const int* __restrict__ bins,
                                                        const int* __restrict__ rowids,
                                                        const float* __restrict__ embed_avg,
                                                        const float* __restrict__ out_cs,
                                                        const float* __restrict__ ntot,
                                                        float* __restrict__ out_q,
                                                        float* __restrict__ out_norm) {
    int tid = threadIdx.x;
    int lane = tid & 63;
    int k = blockIdx.x * 4 + (tid >> 6);
    int beg = offsets[k];
    int cnt = bins[k];
    float2 qv = ((const float2*)(embed + (size_t)k * DIM))[lane];
    float2 acc = {0.f, 0.f};
    for (int i = 0; i < cnt; ++i) {
        int row = rowids[beg + i];
        float2 v = ((const float2*)(x + (size_t)row * DIM))[lane];
        acc.x += v.x;
        acc.y += v.y;
        ((float2*)(out_q + (size_t)row * DIM))[lane] = qv;
    }
    float nt = *ntot;
    float cs = out_cs[k];
    float cluster = (cs + EPSF) / (nt + (float)KCODES * EPSF) * nt;
    float inv = 1.0f / cluster;
    size_t idx = (size_t)k * DIM + lane * 2;
    float2 ea = *(const float2*)(embed_avg + idx);
    float2 o;
    o.x = (ea.x * DECAYF + (1.0f - DECAYF) * acc.x) * inv;
    o.y = (ea.y * DECAYF + (1.0f - DECAYF) * acc.y) * inv;
    *(float2*)(out_norm + idx) = o;
}

extern "C" void kernel_launch(void* const* d_in, const int* in_sizes, int n_in,
                              void* d_out, int out_size, void* d_ws, size_t ws_size,
                              hipStream_t stream) {
    const float* x            = (const float*)d_in[0];
    const float* embed        = (const float*)d_in[1];
    const float* cluster_size = (const float*)d_in[2];
    const float* embed_avg    = (const float*)d_in[3];

    float* out      = (float*)d_out;
    float* out_q    = out;                               // 4194304
    float* out_ind  = out + 4194304;                     // 32768
    float* out_loss = out_ind + 32768;                   // 1
    float* out_cs   = out_loss + 1;                      // 4096
    float* out_norm = out_cs + 4096;                     // 524288

    // workspace layout (bytes)
    char* ws = (char*)d_ws;
    _Float16* estg = (_Float16*)ws;                      // 2,097,152 (staged split)
    float* e2h   = (float*)(ws + 2097152);               // 16,384
    int*   ind   = (int*)(ws + 2113536);                 // 131,072
    float* loss  = (float*)(ws + 2244608);               // 4 (pad to 256)
    float* ntot  = loss + 1;
    int*   bins  = (int*)(ws + 2244864);                 // 16,384
    int*   offsets = (int*)(ws + 2261248);               // 16,384
    int*   cursor  = (int*)(ws + 2277632);               // 16,384
    int*   rowids  = (int*)(ws + 2294016);               // 131,072

    // zero loss/pad + bins (contiguous, 16.6 KB)
    hipMemsetAsync(ws + 2244608, 0, 256 + 16384, stream);

    esplit_kernel<<<KCODES / 4, 256, 0, stream>>>(embed, estg, e2h);
    argmax_kernel<<<NROWS / 64, 256, 0, stream>>>(x, estg, e2h, ind, out_ind,
                                                  bins, loss);
    scan_kernel<<<1, 1024, 0, stream>>>(bins, cluster_size, loss, offsets, cursor,
                                        out_cs, ntot, out_loss);
    reorder_kernel<<<NROWS / 256, 256, 0, stream>>>(ind, cursor, rowids);
    esum_norm_kernel<<<KCODES / 4, 256, 0, stream>>>(x, embed, offsets, bins, rowids,
                                                     embed_avg, out_cs, ntot,
                                                     out_q, out_norm);
}

// Round 8
// 211.773 us; speedup vs baseline: 11.9908x; 1.5690x over previous
//
#include <hip/hip_runtime.h>

#define NROWS 32768
#define DIM   128
#define KCODES 4096
#define DECAYF 0.8f
#define EPSF 1e-5f
#define COMMITW 0.25f

typedef _Float16 half8 __attribute__((ext_vector_type(8)));
typedef _Float16 half2v __attribute__((ext_vector_type(2)));
typedef float float4v __attribute__((ext_vector_type(4)));

// ---------------- embed -> staged split planes + e2 ----------------
// estg layout (halves): [chunk][slice][code6][8], slice = pl*16 + ks*4 + q.
// 1 KB contiguous per slice -> coalesced global_load_lds staging.
__global__ __launch_bounds__(256) void esplit_kernel(const float* __restrict__ embed,
                                                     _Float16* __restrict__ estg,
                                                     float* __restrict__ e2h) {
    int code = blockIdx.x * 4 + (threadIdx.x >> 6);
    int lane = threadIdx.x & 63;
    float2 v = ((const float2*)(embed + (size_t)code * DIM))[lane];
    float s = v.x * v.x + v.y * v.y;
    #pragma unroll
    for (int off = 32; off > 0; off >>= 1) s += __shfl_down(s, off, 64);
    if (lane == 0) e2h[code] = 0.5f * s;

    int d = lane * 2;
    int ks = d >> 5, q = (d >> 3) & 3, j = d & 7;
    _Float16 h0 = (_Float16)v.x, l0 = (_Float16)(v.x - (float)h0);
    _Float16 h1 = (_Float16)v.y, l1 = (_Float16)(v.y - (float)h1);
    int chunk = code >> 6, c6 = code & 63;
    size_t base = (size_t)chunk * 16384;
    size_t hidx = base + (size_t)(( 0 + ks * 4 + q) * 64 + c6) * 8 + j;
    size_t lidx = base + (size_t)((16 + ks * 4 + q) * 64 + c6) * 8 + j;
    *(half2v*)&estg[hidx] = (half2v){h0, h1};
    *(half2v*)&estg[lidx] = (half2v){l0, l1};
}

// ---------------- MFMA argmax (unchanged from R7) ----------------
__global__ __launch_bounds__(256, 2) void argmax_kernel(const float* __restrict__ x,
                                                        const _Float16* __restrict__ estg,
                                                        const float* __restrict__ e2h,
                                                        int* __restrict__ ind,
                                                        float* __restrict__ out_ind,
                                                        int* __restrict__ bins,
                                                        float* __restrict__ loss) {
    __shared__ _Float16 bs[16384];
    __shared__ float rv[4][64];
    __shared__ int   ri[4][64];
    __shared__ float x2s[64];

    int tid = threadIdx.x;
    int lane = tid & 63;
    int w = tid >> 6;
    int m15 = lane & 15;
    int q = (lane >> 4) & 3;
    int n0 = blockIdx.x * 64;

    half8 Ah[4][4], Al[4][4];
    float xsq[4];
    #pragma unroll
    for (int rt = 0; rt < 4; ++rt) {
        xsq[rt] = 0.f;
        #pragma unroll
        for (int ks = 0; ks < 4; ++ks) {
            const float* p = x + (size_t)(n0 + rt * 16 + m15) * DIM + ks * 32 + q * 8;
            float4 a = *(const float4*)p;
            float4 b = *(const float4*)(p + 4);
            float f[8] = {a.x, a.y, a.z, a.w, b.x, b.y, b.z, b.w};
            half8 H, L;
            #pragma unroll
            for (int e = 0; e < 8; ++e) {
                _Float16 h = (_Float16)f[e];
                H[e] = h;
                L[e] = (_Float16)(f[e] - (float)h);
                xsq[rt] += f[e] * f[e];
            }
            Ah[rt][ks] = H;
            Al[rt][ks] = L;
        }
        xsq[rt] += __shfl_xor(xsq[rt], 16, 64);
        xsq[rt] += __shfl_xor(xsq[rt], 32, 64);
    }
    if (w == 0 && lane < 16) {
        #pragma unroll
        for (int rt = 0; rt < 4; ++rt) x2s[rt * 16 + m15] = xsq[rt];
    }

    float best[4][4];
    int   bidx[4][4];
    #pragma unroll
    for (int rt = 0; rt < 4; ++rt)
        #pragma unroll
        for (int r = 0; r < 4; ++r) { best[rt][r] = -3.0e38f; bidx[rt][r] = 0; }

    for (int chunk = 0; chunk < 64; ++chunk) {
        int c0 = chunk * 64;
        float e2v = e2h[c0 + w * 16 + m15];

        __syncthreads();
        #pragma unroll
        for (int t = 0; t < 8; ++t) {
            int s = w * 8 + t;
            const _Float16* gp = estg + (size_t)chunk * 16384 + s * 512 + lane * 8;
            __builtin_amdgcn_global_load_lds(
                (const __attribute__((address_space(1))) unsigned int*)gp,
                (__attribute__((address_space(3))) unsigned int*)&bs[s * 512],
                16, 0, 0);
        }
        __syncthreads();

        float4v acc[4];
        #pragma unroll
        for (int rt = 0; rt < 4; ++rt) acc[rt] = (float4v){0.f, 0.f, 0.f, 0.f};

        #pragma unroll
        for (int ks = 0; ks < 4; ++ks) {
            const half8 Bh = *(const half8*)&bs[(((0 + ks) * 4 + q) * 64 + w * 16 + m15) * 8];
            const half8 Bl = *(const half8*)&bs[(((4 + ks) * 4 + q) * 64 + w * 16 + m15) * 8];
            #pragma unroll
            for (int rt = 0; rt < 4; ++rt) {
                acc[rt] = __builtin_amdgcn_mfma_f32_16x16x32_f16(Ah[rt][ks], Bh, acc[rt], 0, 0, 0);
                acc[rt] = __builtin_amdgcn_mfma_f32_16x16x32_f16(Al[rt][ks], Bh, acc[rt], 0, 0, 0);
                acc[rt] = __builtin_amdgcn_mfma_f32_16x16x32_f16(Ah[rt][ks], Bl, acc[rt], 0, 0, 0);
            }
        }

        int c = c0 + w * 16 + m15;
        #pragma unroll
        for (int rt = 0; rt < 4; ++rt)
            #pragma unroll
            for (int r = 0; r < 4; ++r) {
                float s = acc[rt][r] - e2v;
                if (s > best[rt][r]) { best[rt][r] = s; bidx[rt][r] = c; }
            }
    }

    #pragma unroll
    for (int rt = 0; rt < 4; ++rt)
        #pragma unroll
        for (int r = 0; r < 4; ++r) {
            float bv = best[rt][r];
            int   bi = bidx[rt][r];
            #pragma unroll
            for (int m = 1; m <= 8; m <<= 1) {
                float ov = __shfl_xor(bv, m, 64);
                int   oi = __shfl_xor(bi, m, 64);
                if (ov > bv || (ov == bv && oi < bi)) { bv = ov; bi = oi; }
            }
            if (m15 == 0) {
                int rl = rt * 16 + q * 4 + r;
                rv[w][rl] = bv;
                ri[w][rl] = bi;
            }
        }
    __syncthreads();
    if (tid < 64) {
        float bv = rv[0][tid];
        int   bi = ri[0][tid];
        #pragma unroll
        for (int ww = 1; ww < 4; ++ww) {
            float ov = rv[ww][tid];
            int   oi = ri[ww][tid];
            if (ov > bv || (ov == bv && oi < bi)) { bv = ov; bi = oi; }
        }
        ind[n0 + tid] = bi;
        out_ind[n0 + tid] = (float)bi;
        atomicAdd(&bins[bi], 1);
        float lp = x2s[tid] - 2.0f * bv;
        #pragma unroll
        for (int off = 32; off > 0; off >>= 1) lp += __shfl_down(lp, off, 64);
        if (tid == 0) atomicAdd(loss, lp);
    }
}

// ---------------- scan: offsets/cursor + out_cs + ntot + out_loss ----------
__global__ __launch_bounds__(1024) void scan_kernel(const int* __restrict__ bins,
                                                    const float* __restrict__ cluster_size,
                                                    const float* __restrict__ loss,
                                                    int* __restrict__ offsets,
                                                    int* __restrict__ cursor,
                                                    float* __restrict__ out_cs,
                                                    float* __restrict__ ntot,
                                                    float* __restrict__ out_loss) {
    __shared__ int sdata[1024];
    __shared__ float fred[1024];
    int t = threadIdx.x;
    int b[4];
    float cs[4];
    float csum = 0.f;
    int s = 0;
    #pragma unroll
    for (int e = 0; e < 4; ++e) {
        b[e] = bins[t * 4 + e];
        s += b[e];
        cs[e] = cluster_size[t * 4 + e] * DECAYF + (1.0f - DECAYF) * (float)b[e];
        csum += cs[e];
    }
    int mysum = s;
    sdata[t] = s;
    __syncthreads();
    for (int off = 1; off < 1024; off <<= 1) {
        int v = (t >= off) ? sdata[t - off] : 0;
        __syncthreads();
        sdata[t] += v;
        __syncthreads();
    }
    int ex = sdata[t] - mysum;
    #pragma unroll
    for (int e = 0; e < 4; ++e) {
        offsets[t * 4 + e] = ex;
        cursor[t * 4 + e] = ex;
        out_cs[t * 4 + e] = cs[e];
        ex += b[e];
    }
    fred[t] = csum;
    __syncthreads();
    for (int off = 512; off > 0; off >>= 1) {
        if (t < off) fred[t] += fred[t + off];
        __syncthreads();
    }
    if (t == 0) {
        *ntot = fred[0];
        *out_loss = COMMITW * (*loss) / (float)((size_t)NROWS * DIM);
    }
}

// ---------------- reorder rows by code (also emit sorted code list) --------
__global__ __launch_bounds__(256) void reorder_kernel(const int* __restrict__ ind,
                                                      int* __restrict__ cursor,
                                                      int* __restrict__ rowids,
                                                      int* __restrict__ codesorted) {
    int row = blockIdx.x * 256 + threadIdx.x;
    int k = ind[row];
    int pos = atomicAdd(&cursor[k], 1);
    rowids[pos] = row;
    codesorted[pos] = k;
}

// ---------------- segmented esum + out_q: fixed 16-row windows -------------
// One wave per window of 16 consecutive sorted rows. Runs of equal code
// flush to esum: direct store if the code's whole segment is inside the
// window, atomicAdd if it crosses a window boundary. Bounded work per wave
// regardless of segment-length skew.
#define WROWS 16
__global__ __launch_bounds__(256) void segred_kernel(const float* __restrict__ x,
                                                     const float* __restrict__ embed,
                                                     const int* __restrict__ rowids,
                                                     const int* __restrict__ codesorted,
                                                     const int* __restrict__ offsets,
                                                     const int* __restrict__ bins,
                                                     float* __restrict__ esum,
                                                     float* __restrict__ out_q) {
    int tid = threadIdx.x;
    int lane = tid & 63;
    int wv = blockIdx.x * 4 + (tid >> 6);    // window id, 0..2047
    int w0 = wv * WROWS;

    int i16 = lane & (WROWS - 1);
    int rowv = rowids[w0 + i16];
    int kv   = codesorted[w0 + i16];

    // preload all 16 rows' x data (independent loads -> high MLP)
    float2 xv[WROWS];
    #pragma unroll
    for (int i = 0; i < WROWS; ++i) {
        int row = __shfl(rowv, i, 64);
        xv[i] = ((const float2*)(x + (size_t)row * DIM))[lane];
    }

    int curk = __shfl(kv, 0, 64);
    float2 qv = ((const float2*)(embed + (size_t)curk * DIM))[lane];
    float2 acc = {0.f, 0.f};

    #pragma unroll
    for (int i = 0; i < WROWS; ++i) {
        int row = __shfl(rowv, i, 64);
        int k   = __shfl(kv, i, 64);
        if (k != curk) {   // wave-uniform branch
            int sbeg = offsets[curk];
            int send = sbeg + bins[curk];
            float* ep = esum + (size_t)curk * DIM + lane * 2;
            if (sbeg >= w0 && send <= w0 + WROWS) {
                *(float2*)ep = acc;
            } else {
                atomicAdd(ep, acc.x);
                atomicAdd(ep + 1, acc.y);
            }
            curk = k;
            acc = (float2){0.f, 0.f};
            qv = ((const float2*)(embed + (size_t)curk * DIM))[lane];
        }
        acc.x += xv[i].x;
        acc.y += xv[i].y;
        ((float2*)(out_q + (size_t)row * DIM))[lane] = qv;
    }
    {
        int sbeg = offsets[curk];
        int send = sbeg + bins[curk];
        float* ep = esum + (size_t)curk * DIM + lane * 2;
        if (sbeg >= w0 && send <= w0 + WROWS) {
            *(float2*)ep = acc;
        } else {
            atomicAdd(ep, acc.x);
            atomicAdd(ep + 1, acc.y);
        }
    }
}

// ---------------- norm: out_norm from esum (streaming) ----------------
__global__ __launch_bounds__(256) void norm_kernel(const float* __restrict__ esum,
                                                   const float* __restrict__ embed_avg,
                                                   const float* __restrict__ out_cs,
                                                   const float* __restrict__ ntot,
                                                   float* __restrict__ out_norm) {
    int idx = blockIdx.x * 256 + threadIdx.x;        // float2 index
    int k = idx >> 6;
    float nt = *ntot;
    float cs = out_cs[k];
    float cluster = (cs + EPSF) / (nt + (float)KCODES * EPSF) * nt;
    float inv = 1.0f / cluster;
    float2 es = ((const float2*)esum)[idx];
    float2 ea = ((const float2*)embed_avg)[idx];
    float2 o;
    o.x = (ea.x * DECAYF + (1.0f - DECAYF) * es.x) * inv;
    o.y = (ea.y * DECAYF + (1.0f - DECAYF) * es.y) * inv;
    ((float2*)out_norm)[idx] = o;
}

extern "C" void kernel_launch(void* const* d_in, const int* in_sizes, int n_in,
                              void* d_out, int out_size, void* d_ws, size_t ws_size,
                              hipStream_t stream) {
    const float* x            = (const float*)d_in[0];
    const float* embed        = (const float*)d_in[1];
    const float* cluster_size = (const float*)d_in[2];
    const float* embed_avg    = (const float*)d_in[3];

    float* out      = (float*)d_out;
    float* out_q    = out;                               // 4194304
    float* out_ind  = out + 4194304;                     // 32768
    float* out_loss = out_ind + 32768;                   // 1
    float* out_cs   = out_loss + 1;                      // 4096
    float* out_norm = out_cs + 4096;                     // 524288

    // workspace layout (bytes)
    char* ws = (char*)d_ws;
    _Float16* estg = (_Float16*)ws;                      // 2,097,152
    float* e2h   = (float*)(ws + 2097152);               // 16,384
    int*   ind   = (int*)(ws + 2113536);                 // 131,072
    int*   offsets = (int*)(ws + 2244608);               // 16,384
    int*   cursor  = (int*)(ws + 2260992);               // 16,384
    int*   rowids  = (int*)(ws + 2277376);               // 131,072
    int*   codesorted = (int*)(ws + 2408448);            // 131,072
    float* loss  = (float*)(ws + 2539520);               // 4 (pad to 256)
    float* ntot  = loss + 1;
    int*   bins  = (int*)(ws + 2539776);                 // 16,384
    float* esum  = (float*)(ws + 2556160);               // 2,097,152

    // zero loss/pad + bins + esum (contiguous)
    hipMemsetAsync(ws + 2539520, 0, 256 + 16384 + 2097152, stream);

    esplit_kernel<<<KCODES / 4, 256, 0, stream>>>(embed, estg, e2h);
    argmax_kernel<<<NROWS / 64, 256, 0, stream>>>(x, estg, e2h, ind, out_ind,
                                                  bins, loss);
    scan_kernel<<<1, 1024, 0, stream>>>(bins, cluster_size, loss, offsets, cursor,
                                        out_cs, ntot, out_loss);
    reorder_kernel<<<NROWS / 256, 256, 0, stream>>>(ind, cursor, rowids, codesorted);
    segred_kernel<<<NROWS / WROWS / 4, 256, 0, stream>>>(x, embed, rowids, codesorted,
                                                         offsets, bins, esum, out_q);
    norm_kernel<<<KCODES * DIM / 2 / 256, 256, 0, stream>>>(esum, embed_avg, out_cs,
                                                            ntot, out_norm);
}

// Round 9
// 199.791 us; speedup vs baseline: 12.7099x; 1.0600x over previous
//
#include <hip/hip_runtime.h>

#define NROWS 32768
#define DIM   128
#define KCODES 4096
#define DECAYF 0.8f
#define EPSF 1e-5f
#define COMMITW 0.25f

typedef _Float16 half8 __attribute__((ext_vector_type(8)));
typedef _Float16 half2v __attribute__((ext_vector_type(2)));
typedef float float4v __attribute__((ext_vector_type(4)));

// ---------------- embed -> staged split planes + e2 ----------------
// estg layout (halves): [chunk][slice][code6][8], slice = pl*16 + ks*4 + q.
// This is exactly MFMA B-fragment order: a wave's (m15,q) lanes read
// contiguous 256 B runs -> direct coalesced register loads, no LDS needed.
__global__ __launch_bounds__(256) void esplit_kernel(const float* __restrict__ embed,
                                                     _Float16* __restrict__ estg,
                                                     float* __restrict__ e2h) {
    int code = blockIdx.x * 4 + (threadIdx.x >> 6);
    int lane = threadIdx.x & 63;
    float2 v = ((const float2*)(embed + (size_t)code * DIM))[lane];
    float s = v.x * v.x + v.y * v.y;
    #pragma unroll
    for (int off = 32; off > 0; off >>= 1) s += __shfl_down(s, off, 64);
    if (lane == 0) e2h[code] = 0.5f * s;

    int d = lane * 2;
    int ks = d >> 5, q = (d >> 3) & 3, j = d & 7;
    _Float16 h0 = (_Float16)v.x, l0 = (_Float16)(v.x - (float)h0);
    _Float16 h1 = (_Float16)v.y, l1 = (_Float16)(v.y - (float)h1);
    int chunk = code >> 6, c6 = code & 63;
    size_t base = (size_t)chunk * 16384;
    size_t hidx = base + (size_t)(( 0 + ks * 4 + q) * 64 + c6) * 8 + j;
    size_t lidx = base + (size_t)((16 + ks * 4 + q) * 64 + c6) * 8 + j;
    *(half2v*)&estg[hidx] = (half2v){h0, h1};
    *(half2v*)&estg[lidx] = (half2v){l0, l1};
}

// ---------------- MFMA argmax: barrier-free K-loop, register dbuf ----------
// score = x.e - 0.5|e|^2. fp16 2-way split, 3 products (hh, lh, hl).
// Block: 4 waves, 64 rows; every wave holds all 64 rows' A-frags resident
// (128 VGPRs). Wave w sweeps code-tile j=w of every 64-code chunk, loading
// its 8 B-frags straight from L2-hot estg into a register double-buffer.
// NO LDS staging, NO per-chunk barriers -> compiler emits fine-grained
// s_waitcnt vmcnt(N) MFMA/load interleave (AITER-style pipeline).
__global__ __launch_bounds__(256, 2) void argmax_kernel(const float* __restrict__ x,
                                                        const _Float16* __restrict__ estg,
                                                        const float* __restrict__ e2h,
                                                        int* __restrict__ ind,
                                                        float* __restrict__ out_ind,
                                                        int* __restrict__ bins,
                                                        float* __restrict__ loss) {
    __shared__ float rv[4][64];
    __shared__ int   ri[4][64];
    __shared__ float x2s[64];

    int tid = threadIdx.x;
    int lane = tid & 63;
    int w = tid >> 6;
    int m15 = lane & 15;
    int q = (lane >> 4) & 3;
    int n0 = blockIdx.x * 64;

    // A frags for all 64 rows, resident; also per-row |x|^2 (fp32 exact)
    half8 Ah[4][4], Al[4][4];
    float xsq[4];
    #pragma unroll
    for (int rt = 0; rt < 4; ++rt) {
        xsq[rt] = 0.f;
        #pragma unroll
        for (int ks = 0; ks < 4; ++ks) {
            const float* p = x + (size_t)(n0 + rt * 16 + m15) * DIM + ks * 32 + q * 8;
            float4 a = *(const float4*)p;
            float4 b = *(const float4*)(p + 4);
            float f[8] = {a.x, a.y, a.z, a.w, b.x, b.y, b.z, b.w};
            half8 H, L;
            #pragma unroll
            for (int e = 0; e < 8; ++e) {
                _Float16 h = (_Float16)f[e];
                H[e] = h;
                L[e] = (_Float16)(f[e] - (float)h);
                xsq[rt] += f[e] * f[e];
            }
            Ah[rt][ks] = H;
            Al[rt][ks] = L;
        }
        xsq[rt] += __shfl_xor(xsq[rt], 16, 64);
        xsq[rt] += __shfl_xor(xsq[rt], 32, 64);
    }
    if (w == 0 && lane < 16) {
        #pragma unroll
        for (int rt = 0; rt < 4; ++rt) x2s[rt * 16 + m15] = xsq[rt];
    }

    float best[4][4];
    int   bidx[4][4];
    #pragma unroll
    for (int rt = 0; rt < 4; ++rt)
        #pragma unroll
        for (int r = 0; r < 4; ++r) { best[rt][r] = -3.0e38f; bidx[rt][r] = 0; }

    // B fragment base for this wave/lane within a chunk
    const _Float16* bbase = estg + (size_t)(w * 16 + m15) * 8 + (size_t)q * 512;
    const int cm = w * 16 + m15;

    half8 B0h[4], B0l[4], B1h[4], B1l[4];
    float e20, e21;

    // prefetch chunk 0 -> buf0
    {
        const _Float16* cb = bbase;
        #pragma unroll
        for (int ks = 0; ks < 4; ++ks) {
            B0h[ks] = *(const half8*)(cb + ks * 2048);
            B0l[ks] = *(const half8*)(cb + 8192 + ks * 2048);
        }
        e20 = e2h[cm];
    }

    #pragma unroll 1
    for (int ch = 0; ch < 64; ch += 2) {
        // prefetch ch+1 -> buf1 (ch+1 <= 63 always)
        {
            const _Float16* cb = bbase + (size_t)(ch + 1) * 16384;
            #pragma unroll
            for (int ks = 0; ks < 4; ++ks) {
                B1h[ks] = *(const half8*)(cb + ks * 2048);
                B1l[ks] = *(const half8*)(cb + 8192 + ks * 2048);
            }
            e21 = e2h[(ch + 1) * 64 + cm];
        }
        // compute ch from buf0
        {
            float4v acc[4];
            #pragma unroll
            for (int rt = 0; rt < 4; ++rt) acc[rt] = (float4v){0.f, 0.f, 0.f, 0.f};
            #pragma unroll
            for (int ks = 0; ks < 4; ++ks)
                #pragma unroll
                for (int rt = 0; rt < 4; ++rt) {
                    acc[rt] = __builtin_amdgcn_mfma_f32_16x16x32_f16(Ah[rt][ks], B0h[ks], acc[rt], 0, 0, 0);
                    acc[rt] = __builtin_amdgcn_mfma_f32_16x16x32_f16(Al[rt][ks], B0h[ks], acc[rt], 0, 0, 0);
                    acc[rt] = __builtin_amdgcn_mfma_f32_16x16x32_f16(Ah[rt][ks], B0l[ks], acc[rt], 0, 0, 0);
                }
            int c = ch * 64 + cm;
            #pragma unroll
            for (int rt = 0; rt < 4; ++rt)
                #pragma unroll
                for (int r = 0; r < 4; ++r) {
                    float s = acc[rt][r] - e20;
                    if (s > best[rt][r]) { best[rt][r] = s; bidx[rt][r] = c; }
                }
        }
        // prefetch ch+2 -> buf0
        if (ch + 2 < 64) {
            const _Float16* cb = bbase + (size_t)(ch + 2) * 16384;
            #pragma unroll
            for (int ks = 0; ks < 4; ++ks) {
                B0h[ks] = *(const half8*)(cb + ks * 2048);
                B0l[ks] = *(const half8*)(cb + 8192 + ks * 2048);
            }
            e20 = e2h[(ch + 2) * 64 + cm];
        }
        // compute ch+1 from buf1
        {
            float4v acc[4];
            #pragma unroll
            for (int rt = 0; rt < 4; ++rt) acc[rt] = (float4v){0.f, 0.f, 0.f, 0.f};
            #pragma unroll
            for (int ks = 0; ks < 4; ++ks)
                #pragma unroll
                for (int rt = 0; rt < 4; ++rt) {
                    acc[rt] = __builtin_amdgcn_mfma_f32_16x16x32_f16(Ah[rt][ks], B1h[ks], acc[rt], 0, 0, 0);
                    acc[rt] = __builtin_amdgcn_mfma_f32_16x16x32_f16(Al[rt][ks], B1h[ks], acc[rt], 0, 0, 0);
                    acc[rt] = __builtin_amdgcn_mfma_f32_16x16x32_f16(Ah[rt][ks], B1l[ks], acc[rt], 0, 0, 0);
                }
            int c = (ch + 1) * 64 + cm;
            #pragma unroll
            for (int rt = 0; rt < 4; ++rt)
                #pragma unroll
                for (int r = 0; r < 4; ++r) {
                    float s = acc[rt][r] - e21;
                    if (s > best[rt][r]) { best[rt][r] = s; bidx[rt][r] = c; }
                }
        }
    }

    // reduce across the 16 code-lanes (m15); min index on ties
    #pragma unroll
    for (int rt = 0; rt < 4; ++rt)
        #pragma unroll
        for (int r = 0; r < 4; ++r) {
            float bv = best[rt][r];
            int   bi = bidx[rt][r];
            #pragma unroll
            for (int m = 1; m <= 8; m <<= 1) {
                float ov = __shfl_xor(bv, m, 64);
                int   oi = __shfl_xor(bi, m, 64);
                if (ov > bv || (ov == bv && oi < bi)) { bv = ov; bi = oi; }
            }
            if (m15 == 0) {
                int rl = rt * 16 + q * 4 + r;
                rv[w][rl] = bv;
                ri[w][rl] = bi;
            }
        }
    __syncthreads();
    if (tid < 64) {
        float bv = rv[0][tid];
        int   bi = ri[0][tid];
        #pragma unroll
        for (int ww = 1; ww < 4; ++ww) {
            float ov = rv[ww][tid];
            int   oi = ri[ww][tid];
            if (ov > bv || (ov == bv && oi < bi)) { bv = ov; bi = oi; }
        }
        ind[n0 + tid] = bi;
        out_ind[n0 + tid] = (float)bi;
        atomicAdd(&bins[bi], 1);
        float lp = x2s[tid] - 2.0f * bv;
        #pragma unroll
        for (int off = 32; off > 0; off >>= 1) lp += __shfl_down(lp, off, 64);
        if (tid == 0) atomicAdd(loss, lp);
    }
}

// ---------------- scan: shuffle-based, 2 barriers ----------------
__global__ __launch_bounds__(1024) void scan_kernel(const int* __restrict__ bins,
                                                    const float* __restrict__ cluster_size,
                                                    const float* __restrict__ loss,
                                                    int* __restrict__ offsets,
                                                    int* __restrict__ cursor,
                                                    float* __restrict__ out_cs,
                                                    float* __restrict__ ntot,
                                                    float* __restrict__ out_loss) {
    __shared__ int   wtot[16];
    __shared__ float fred[16];
    int t = threadIdx.x;
    int lane = t & 63, wv = t >> 6;
    int b[4];
    float cs[4];
    float csum = 0.f;
    int s = 0;
    #pragma unroll
    for (int e = 0; e < 4; ++e) {
        b[e] = bins[t * 4 + e];
        s += b[e];
        cs[e] = cluster_size[t * 4 + e] * DECAYF + (1.0f - DECAYF) * (float)b[e];
        csum += cs[e];
    }
    // inclusive wave scan of s
    int sc = s;
    #pragma unroll
    for (int off = 1; off < 64; off <<= 1) {
        int v = __shfl_up(sc, off, 64);
        if (lane >= off) sc += v;
    }
    // wave reduce csum
    float fc = csum;
    #pragma unroll
    for (int off = 32; off > 0; off >>= 1) fc += __shfl_down(fc, off, 64);
    if (lane == 63) wtot[wv] = sc;
    if (lane == 0) fred[wv] = fc;
    __syncthreads();
    if (t < 16) {
        int v = wtot[t];
        int scv = v;
        #pragma unroll
        for (int off = 1; off < 16; off <<= 1) {
            int u = __shfl_up(scv, off, 64);
            if (t >= off) scv += u;
        }
        wtot[t] = scv - v;   // exclusive prefix of wave totals
    }
    if (t == 0) {
        float tot = 0.f;
        #pragma unroll
        for (int i = 0; i < 16; ++i) tot += fred[i];
        *ntot = tot;
        *out_loss = COMMITW * (*loss) / (float)((size_t)NROWS * DIM);
    }
    __syncthreads();
    int ex = sc - s + wtot[wv];
    #pragma unroll
    for (int e = 0; e < 4; ++e) {
        offsets[t * 4 + e] = ex;
        cursor[t * 4 + e] = ex;
        out_cs[t * 4 + e] = cs[e];
        ex += b[e];
    }
}

// ---------------- reorder rows by code (also emit sorted code list) --------
__global__ __launch_bounds__(256) void reorder_kernel(const int* __restrict__ ind,
                                                      int* __restrict__ cursor,
                                                      int* __restrict__ rowids,
                                                      int* __restrict__ codesorted) {
    int row = blockIdx.x * 256 + threadIdx.x;
    int k = ind[row];
    int pos = atomicAdd(&cursor[k], 1);
    rowids[pos] = row;
    codesorted[pos] = k;
}

// ---------------- segmented esum + out_q: fixed 16-row windows -------------
#define WROWS 16
__global__ __launch_bounds__(256) void segred_kernel(const float* __restrict__ x,
                                                     const float* __restrict__ embed,
                                                     const int* __restrict__ rowids,
                                                     const int* __restrict__ codesorted,
                                                     const int* __restrict__ offsets,
                                                     const int* __restrict__ bins,
                                                     float* __restrict__ esum,
                                                     float* __restrict__ out_q) {
    int tid = threadIdx.x;
    int lane = tid & 63;
    int wv = blockIdx.x * 4 + (tid >> 6);
    int w0 = wv * WROWS;

    int i16 = lane & (WROWS - 1);
    int rowv = rowids[w0 + i16];
    int kv   = codesorted[w0 + i16];

    float2 xv[WROWS];
    #pragma unroll
    for (int i = 0; i < WROWS; ++i) {
        int row = __shfl(rowv, i, 64);
        xv[i] = ((const float2*)(x + (size_t)row * DIM))[lane];
    }

    int curk = __shfl(kv, 0, 64);
    float2 qv = ((const float2*)(embed + (size_t)curk * DIM))[lane];
    float2 acc = {0.f, 0.f};

    #pragma unroll
    for (int i = 0; i < WROWS; ++i) {
        int row = __shfl(rowv, i, 64);
        int k   = __shfl(kv, i, 64);
        if (k != curk) {
            int sbeg = offsets[curk];
            int send = sbeg + bins[curk];
            float* ep = esum + (size_t)curk * DIM + lane * 2;
            if (sbeg >= w0 && send <= w0 + WROWS) {
                *(float2*)ep = acc;
            } else {
                atomicAdd(ep, acc.x);
                atomicAdd(ep + 1, acc.y);
            }
            curk = k;
            acc = (float2){0.f, 0.f};
            qv = ((const float2*)(embed + (size_t)curk * DIM))[lane];
        }
        acc.x += xv[i].x;
        acc.y += xv[i].y;
        ((float2*)(out_q + (size_t)row * DIM))[lane] = qv;
    }
    {
        int sbeg = offsets[curk];
        int send = sbeg + bins[curk];
        float* ep = esum + (size_t)curk * DIM + lane * 2;
        if (sbeg >= w0 && send <= w0 + WROWS) {
            *(float2*)ep = acc;
        } else {
            atomicAdd(ep, acc.x);
            atomicAdd(ep + 1, acc.y);
        }
    }
}

// ---------------- norm: out_norm from esum (streaming) ----------------
__global__ __launch_bounds__(256) void norm_kernel(const float* __restrict__ esum,
                                                   const float* __restrict__ embed_avg,
                                                   const float* __restrict__ out_cs,
                                                   const float* __restrict__ ntot,
                                                   float* __restrict__ out_norm) {
    int idx = blockIdx.x * 256 + threadIdx.x;
    int k = idx >> 6;
    float nt = *ntot;
    float cs = out_cs[k];
    float cluster = (cs + EPSF) / (nt + (float)KCODES * EPSF) * nt;
    float inv = 1.0f / cluster;
    float2 es = ((const float2*)esum)[idx];
    float2 ea = ((const float2*)embed_avg)[idx];
    float2 o;
    o.x = (ea.x * DECAYF + (1.0f - DECAYF) * es.x) * inv;
    o.y = (ea.y * DECAYF + (1.0f - DECAYF) * es.y) * inv;
    ((float2*)out_norm)[idx] = o;
}

extern "C" void kernel_launch(void* const* d_in, const int* in_sizes, int n_in,
                              void* d_out, int out_size, void* d_ws, size_t ws_size,
                              hipStream_t stream) {
    const float* x            = (const float*)d_in[0];
    const float* embed        = (const float*)d_in[1];
    const float* cluster_size = (const float*)d_in[2];
    const float* embed_avg    = (const float*)d_in[3];

    float* out      = (float*)d_out;
    float* out_q    = out;                               // 4194304
    float* out_ind  = out + 4194304;                     // 32768
    float* out_loss = out_ind + 32768;                   // 1
    float* out_cs   = out_loss + 1;                      // 4096
    float* out_norm = out_cs + 4096;                     // 524288

    // workspace layout (bytes)
    char* ws = (char*)d_ws;
    _Float16* estg = (_Float16*)ws;                      // 2,097,152
    float* e2h   = (float*)(ws + 2097152);               // 16,384
    int*   ind   = (int*)(ws + 2113536);                 // 131,072
    int*   offsets = (int*)(ws + 2244608);               // 16,384
    int*   cursor  = (int*)(ws + 2260992);               // 16,384
    int*   rowids  = (int*)(ws + 2277376);               // 131,072
    int*   codesorted = (int*)(ws + 2408448);            // 131,072
    float* loss  = (float*)(ws + 2539520);               // 4 (pad to 256)
    float* ntot  = loss + 1;
    int*   bins  = (int*)(ws + 2539776);                 // 16,384
    float* esum  = (float*)(ws + 2556160);               // 2,097,152

    // zero loss/pad + bins + esum (contiguous)
    hipMemsetAsync(ws + 2539520, 0, 256 + 16384 + 2097152, stream);

    esplit_kernel<<<KCODES / 4, 256, 0, stream>>>(embed, estg, e2h);
    argmax_kernel<<<NROWS / 64, 256, 0, stream>>>(x, estg, e2h, ind, out_ind,
                                                  bins, loss);
    scan_kernel<<<1, 1024, 0, stream>>>(bins, cluster_size, loss, offsets, cursor,
                                        out_cs, ntot, out_loss);
    reorder_kernel<<<NROWS / 256, 256, 0, stream>>>(ind, cursor, rowids, codesorted);
    segred_kernel<<<NROWS / WROWS / 4, 256, 0, stream>>>(x, embed, rowids, codesorted,
                                                         offsets, bins, esum, out_q);
    norm_kernel<<<KCODES * DIM / 2 / 256, 256, 0, stream>>>(esum, embed_avg, out_cs,
                                                            ntot, out_norm);
}

// Round 10
// 193.113 us; speedup vs baseline: 13.1494x; 1.0346x over previous
//
#include <hip/hip_runtime.h>

#define NROWS 32768
#define DIM   128
#define KCODES 4096
#define DECAYF 0.8f
#define EPSF 1e-5f
#define COMMITW 0.25f

typedef _Float16 half8 __attribute__((ext_vector_type(8)));
typedef _Float16 half2v __attribute__((ext_vector_type(2)));
typedef float float4v __attribute__((ext_vector_type(4)));

// ---------------- embed -> staged split planes + e2 ----------------
// estg layout (halves): [chunk][slice][code6][8], slice = pl*16 + ks*4 + q.
// Exactly MFMA B-fragment order -> direct coalesced register loads.
__global__ __launch_bounds__(256) void esplit_kernel(const float* __restrict__ embed,
                                                     _Float16* __restrict__ estg,
                                                     float* __restrict__ e2h) {
    int code = blockIdx.x * 4 + (threadIdx.x >> 6);
    int lane = threadIdx.x & 63;
    float2 v = ((const float2*)(embed + (size_t)code * DIM))[lane];
    float s = v.x * v.x + v.y * v.y;
    #pragma unroll
    for (int off = 32; off > 0; off >>= 1) s += __shfl_down(s, off, 64);
    if (lane == 0) e2h[code] = 0.5f * s;

    int d = lane * 2;
    int ks = d >> 5, q = (d >> 3) & 3, j = d & 7;
    _Float16 h0 = (_Float16)v.x, l0 = (_Float16)(v.x - (float)h0);
    _Float16 h1 = (_Float16)v.y, l1 = (_Float16)(v.y - (float)h1);
    int chunk = code >> 6, c6 = code & 63;
    size_t base = (size_t)chunk * 16384;
    size_t hidx = base + (size_t)(( 0 + ks * 4 + q) * 64 + c6) * 8 + j;
    size_t lidx = base + (size_t)((16 + ks * 4 + q) * 64 + c6) * 8 + j;
    *(half2v*)&estg[hidx] = (half2v){h0, h1};
    *(half2v*)&estg[lidx] = (half2v){l0, l1};
}

// ---------------- MFMA argmax: 128 rows/block, barrier-free K-loop ---------
// score = x.e - 0.5|e|^2 (folded into acc init). fp16 2-way split, 3 products.
// 512 thr / 8 waves: wave w -> code-tile j=w&3, row-half rh=w>>2 (64 rows
// A-resident = 128 VGPRs/wave, unchanged). Waves j and j+4 read the SAME
// B-frags ~concurrently -> L1/L2 line sharing; block-level B traffic is
// 2 MB per 128 rows (half of R9). Register dbuf, no per-chunk barriers.
__global__ __launch_bounds__(512, 2) void argmax_kernel(const float* __restrict__ x,
                                                        const _Float16* __restrict__ estg,
                                                        const float* __restrict__ e2h,
                                                        int* __restrict__ ind,
                                                        float* __restrict__ out_ind,
                                                        int* __restrict__ bins,
                                                        float* __restrict__ loss) {
    __shared__ float rv[8][64];
    __shared__ int   ri[8][64];
    __shared__ float x2s[128];

    int tid = threadIdx.x;
    int lane = tid & 63;
    int w = tid >> 6;
    int j = w & 3;
    int rh = w >> 2;
    int m15 = lane & 15;
    int q = (lane >> 4) & 3;
    int n0 = blockIdx.x * 128;

    // A frags for this wave's 64 rows (rows n0 + rh*64 + rt*16 + m15)
    half8 Ah[4][4], Al[4][4];
    float xsq[4];
    #pragma unroll
    for (int rt = 0; rt < 4; ++rt) {
        xsq[rt] = 0.f;
        #pragma unroll
        for (int ks = 0; ks < 4; ++ks) {
            const float* p = x + (size_t)(n0 + rh * 64 + rt * 16 + m15) * DIM + ks * 32 + q * 8;
            float4 a = *(const float4*)p;
            float4 b = *(const float4*)(p + 4);
            float f[8] = {a.x, a.y, a.z, a.w, b.x, b.y, b.z, b.w};
            half8 H, L;
            #pragma unroll
            for (int e = 0; e < 8; ++e) {
                _Float16 h = (_Float16)f[e];
                H[e] = h;
                L[e] = (_Float16)(f[e] - (float)h);
                xsq[rt] += f[e] * f[e];
            }
            Ah[rt][ks] = H;
            Al[rt][ks] = L;
        }
        xsq[rt] += __shfl_xor(xsq[rt], 16, 64);
        xsq[rt] += __shfl_xor(xsq[rt], 32, 64);
    }
    if (j == 0 && lane < 16) {
        #pragma unroll
        for (int rt = 0; rt < 4; ++rt) x2s[rh * 64 + rt * 16 + m15] = xsq[rt];
    }

    float best[4][4];
    int   bidx[4][4];
    #pragma unroll
    for (int rt = 0; rt < 4; ++rt)
        #pragma unroll
        for (int r = 0; r < 4; ++r) { best[rt][r] = -3.0e38f; bidx[rt][r] = 0; }

    // B fragment base for this wave/lane within a chunk
    const _Float16* bbase = estg + (size_t)(j * 16 + m15) * 8 + (size_t)q * 512;
    const int cm = j * 16 + m15;

    half8 B0h[4], B0l[4], B1h[4], B1l[4];
    float e20, e21;

    // prefetch chunk 0 -> buf0
    {
        const _Float16* cb = bbase;
        #pragma unroll
        for (int ks = 0; ks < 4; ++ks) {
            B0h[ks] = *(const half8*)(cb + ks * 2048);
            B0l[ks] = *(const half8*)(cb + 8192 + ks * 2048);
        }
        e20 = e2h[cm];
    }

    #pragma unroll 1
    for (int ch = 0; ch < 64; ch += 2) {
        // prefetch ch+1 -> buf1
        {
            const _Float16* cb = bbase + (size_t)(ch + 1) * 16384;
            #pragma unroll
            for (int ks = 0; ks < 4; ++ks) {
                B1h[ks] = *(const half8*)(cb + ks * 2048);
                B1l[ks] = *(const half8*)(cb + 8192 + ks * 2048);
            }
            e21 = e2h[(ch + 1) * 64 + cm];
        }
        // compute ch from buf0 (acc init = -e2 folds the bias in)
        {
            float4v acc[4];
            #pragma unroll
            for (int rt = 0; rt < 4; ++rt) acc[rt] = (float4v){-e20, -e20, -e20, -e20};
            #pragma unroll
            for (int ks = 0; ks < 4; ++ks)
                #pragma unroll
                for (int rt = 0; rt < 4; ++rt) {
                    acc[rt] = __builtin_amdgcn_mfma_f32_16x16x32_f16(Ah[rt][ks], B0h[ks], acc[rt], 0, 0, 0);
                    acc[rt] = __builtin_amdgcn_mfma_f32_16x16x32_f16(Al[rt][ks], B0h[ks], acc[rt], 0, 0, 0);
                    acc[rt] = __builtin_amdgcn_mfma_f32_16x16x32_f16(Ah[rt][ks], B0l[ks], acc[rt], 0, 0, 0);
                }
            int c = ch * 64 + cm;
            #pragma unroll
            for (int rt = 0; rt < 4; ++rt)
                #pragma unroll
                for (int r = 0; r < 4; ++r) {
                    float s = acc[rt][r];
                    if (s > best[rt][r]) { best[rt][r] = s; bidx[rt][r] = c; }
                }
        }
        // prefetch ch+2 -> buf0
        if (ch + 2 < 64) {
            const _Float16* cb = bbase + (size_t)(ch + 2) * 16384;
            #pragma unroll
            for (int ks = 0; ks < 4; ++ks) {
                B0h[ks] = *(const half8*)(cb + ks * 2048);
                B0l[ks] = *(const half8*)(cb + 8192 + ks * 2048);
            }
            e20 = e2h[(ch + 2) * 64 + cm];
        }
        // compute ch+1 from buf1
        {
            float4v acc[4];
            #pragma unroll
            for (int rt = 0; rt < 4; ++rt) acc[rt] = (float4v){-e21, -e21, -e21, -e21};
            #pragma unroll
            for (int ks = 0; ks < 4; ++ks)
                #pragma unroll
                for (int rt = 0; rt < 4; ++rt) {
                    acc[rt] = __builtin_amdgcn_mfma_f32_16x16x32_f16(Ah[rt][ks], B1h[ks], acc[rt], 0, 0, 0);
                    acc[rt] = __builtin_amdgcn_mfma_f32_16x16x32_f16(Al[rt][ks], B1h[ks], acc[rt], 0, 0, 0);
                    acc[rt] = __builtin_amdgcn_mfma_f32_16x16x32_f16(Ah[rt][ks], B1l[ks], acc[rt], 0, 0, 0);
                }
            int c = (ch + 1) * 64 + cm;
            #pragma unroll
            for (int rt = 0; rt < 4; ++rt)
                #pragma unroll
                for (int r = 0; r < 4; ++r) {
                    float s = acc[rt][r];
                    if (s > best[rt][r]) { best[rt][r] = s; bidx[rt][r] = c; }
                }
        }
    }

    // reduce across the 16 code-lanes (m15); min index on ties
    #pragma unroll
    for (int rt = 0; rt < 4; ++rt)
        #pragma unroll
        for (int r = 0; r < 4; ++r) {
            float bv = best[rt][r];
            int   bi = bidx[rt][r];
            #pragma unroll
            for (int m = 1; m <= 8; m <<= 1) {
                float ov = __shfl_xor(bv, m, 64);
                int   oi = __shfl_xor(bi, m, 64);
                if (ov > bv || (ov == bv && oi < bi)) { bv = ov; bi = oi; }
            }
            if (m15 == 0) {
                int rl = rt * 16 + q * 4 + r;
                rv[w][rl] = bv;
                ri[w][rl] = bi;
            }
        }
    __syncthreads();
    if (tid < 128) {
        int rhh = tid >> 6;
        int rl  = tid & 63;
        float bv = rv[rhh * 4][rl];
        int   bi = ri[rhh * 4][rl];
        #pragma unroll
        for (int jj = 1; jj < 4; ++jj) {
            float ov = rv[rhh * 4 + jj][rl];
            int   oi = ri[rhh * 4 + jj][rl];
            if (ov > bv || (ov == bv && oi < bi)) { bv = ov; bi = oi; }
        }
        ind[n0 + tid] = bi;
        out_ind[n0 + tid] = (float)bi;
        atomicAdd(&bins[bi], 1);
        // commit-loss partial: |x - e_k|^2 = |x|^2 - 2*best_score
        float lp = x2s[tid] - 2.0f * bv;
        #pragma unroll
        for (int off = 32; off > 0; off >>= 1) lp += __shfl_down(lp, off, 64);
        if ((tid & 63) == 0) atomicAdd(loss, lp);
    }
}

// ---------------- scan: shuffle-based, 2 barriers ----------------
__global__ __launch_bounds__(1024) void scan_kernel(const int* __restrict__ bins,
                                                    const float* __restrict__ cluster_size,
                                                    const float* __restrict__ loss,
                                                    int* __restrict__ offsets,
                                                    int* __restrict__ cursor,
                                                    float* __restrict__ out_cs,
                                                    float* __restrict__ ntot,
                                                    float* __restrict__ out_loss) {
    __shared__ int   wtot[16];
    __shared__ float fred[16];
    int t = threadIdx.x;
    int lane = t & 63, wv = t >> 6;
    int b[4];
    float cs[4];
    float csum = 0.f;
    int s = 0;
    #pragma unroll
    for (int e = 0; e < 4; ++e) {
        b[e] = bins[t * 4 + e];
        s += b[e];
        cs[e] = cluster_size[t * 4 + e] * DECAYF + (1.0f - DECAYF) * (float)b[e];
        csum += cs[e];
    }
    int sc = s;
    #pragma unroll
    for (int off = 1; off < 64; off <<= 1) {
        int v = __shfl_up(sc, off, 64);
        if (lane >= off) sc += v;
    }
    float fc = csum;
    #pragma unroll
    for (int off = 32; off > 0; off >>= 1) fc += __shfl_down(fc, off, 64);
    if (lane == 63) wtot[wv] = sc;
    if (lane == 0) fred[wv] = fc;
    __syncthreads();
    if (t < 16) {
        int v = wtot[t];
        int scv = v;
        #pragma unroll
        for (int off = 1; off < 16; off <<= 1) {
            int u = __shfl_up(scv, off, 64);
            if (t >= off) scv += u;
        }
        wtot[t] = scv - v;
    }
    if (t == 0) {
        float tot = 0.f;
        #pragma unroll
        for (int i = 0; i < 16; ++i) tot += fred[i];
        *ntot = tot;
        *out_loss = COMMITW * (*loss) / (float)((size_t)NROWS * DIM);
    }
    __syncthreads();
    int ex = sc - s + wtot[wv];
    #pragma unroll
    for (int e = 0; e < 4; ++e) {
        offsets[t * 4 + e] = ex;
        cursor[t * 4 + e] = ex;
        out_cs[t * 4 + e] = cs[e];
        ex += b[e];
    }
}

// ---------------- reorder rows by code (also emit sorted code list) --------
__global__ __launch_bounds__(256) void reorder_kernel(const int* __restrict__ ind,
                                                      int* __restrict__ cursor,
                                                      int* __restrict__ rowids,
                                                      int* __restrict__ codesorted) {
    int row = blockIdx.x * 256 + threadIdx.x;
    int k = ind[row];
    int pos = atomicAdd(&cursor[k], 1);
    rowids[pos] = row;
    codesorted[pos] = k;
}

// ---------------- segmented esum + out_q: fixed 16-row windows -------------
#define WROWS 16
__global__ __launch_bounds__(256) void segred_kernel(const float* __restrict__ x,
                                                     const float* __restrict__ embed,
                                                     const int* __restrict__ rowids,
                                                     const int* __restrict__ codesorted,
                                                     const int* __restrict__ offsets,
                                                     const int* __restrict__ bins,
                                                     float* __restrict__ esum,
                                                     float* __restrict__ out_q) {
    int tid = threadIdx.x;
    int lane = tid & 63;
    int wv = blockIdx.x * 4 + (tid >> 6);
    int w0 = wv * WROWS;

    int i16 = lane & (WROWS - 1);
    int rowv = rowids[w0 + i16];
    int kv   = codesorted[w0 + i16];

    float2 xv[WROWS];
    #pragma unroll
    for (int i = 0; i < WROWS; ++i) {
        int row = __shfl(rowv, i, 64);
        xv[i] = ((const float2*)(x + (size_t)row * DIM))[lane];
    }

    int curk = __shfl(kv, 0, 64);
    float2 qv = ((const float2*)(embed + (size_t)curk * DIM))[lane];
    float2 acc = {0.f, 0.f};

    #pragma unroll
    for (int i = 0; i < WROWS; ++i) {
        int row = __shfl(rowv, i, 64);
        int k   = __shfl(kv, i, 64);
        if (k != curk) {
            int sbeg = offsets[curk];
            int send = sbeg + bins[curk];
            float* ep = esum + (size_t)curk * DIM + lane * 2;
            if (sbeg >= w0 && send <= w0 + WROWS) {
                *(float2*)ep = acc;
            } else {
                atomicAdd(ep, acc.x);
                atomicAdd(ep + 1, acc.y);
            }
            curk = k;
            acc = (float2){0.f, 0.f};
            qv = ((const float2*)(embed + (size_t)curk * DIM))[lane];
        }
        acc.x += xv[i].x;
        acc.y += xv[i].y;
        ((float2*)(out_q + (size_t)row * DIM))[lane] = qv;
    }
    {
        int sbeg = offsets[curk];
        int send = sbeg + bins[curk];
        float* ep = esum + (size_t)curk * DIM + lane * 2;
        if (sbeg >= w0 && send <= w0 + WROWS) {
            *(float2*)ep = acc;
        } else {
            atomicAdd(ep, acc.x);
            atomicAdd(ep + 1, acc.y);
        }
    }
}

// ---------------- norm: out_norm from esum (streaming) ----------------
__global__ __launch_bounds__(256) void norm_kernel(const float* __restrict__ esum,
                                                   const float* __restrict__ embed_avg,
                                                   const float* __restrict__ out_cs,
                                                   const float* __restrict__ ntot,
                                                   float* __restrict__ out_norm) {
    int idx = blockIdx.x * 256 + threadIdx.x;
    int k = idx >> 6;
    float nt = *ntot;
    float cs = out_cs[k];
    float cluster = (cs + EPSF) / (nt + (float)KCODES * EPSF) * nt;
    float inv = 1.0f / cluster;
    float2 es = ((const float2*)esum)[idx];
    float2 ea = ((const float2*)embed_avg)[idx];
    float2 o;
    o.x = (ea.x * DECAYF + (1.0f - DECAYF) * es.x) * inv;
    o.y = (ea.y * DECAYF + (1.0f - DECAYF) * es.y) * inv;
    ((float2*)out_norm)[idx] = o;
}

extern "C" void kernel_launch(void* const* d_in, const int* in_sizes, int n_in,
                              void* d_out, int out_size, void* d_ws, size_t ws_size,
                              hipStream_t stream) {
    const float* x            = (const float*)d_in[0];
    const float* embed        = (const float*)d_in[1];
    const float* cluster_size = (const float*)d_in[2];
    const float* embed_avg    = (const float*)d_in[3];

    float* out      = (float*)d_out;
    float* out_q    = out;                               // 4194304
    float* out_ind  = out + 4194304;                     // 32768
    float* out_loss = out_ind + 32768;                   // 1
    float* out_cs   = out_loss + 1;                      // 4096
    float* out_norm = out_cs + 4096;                     // 524288

    // workspace layout (bytes)
    char* ws = (char*)d_ws;
    _Float16* estg = (_Float16*)ws;                      // 2,097,152
    float* e2h   = (float*)(ws + 2097152);               // 16,384
    int*   ind   = (int*)(ws + 2113536);                 // 131,072
    int*   offsets = (int*)(ws + 2244608);               // 16,384
    int*   cursor  = (int*)(ws + 2260992);               // 16,384
    int*   rowids  = (int*)(ws + 2277376);               // 131,072
    int*   codesorted = (int*)(ws + 2408448);            // 131,072
    float* loss  = (float*)(ws + 2539520);               // 4 (pad to 256)
    float* ntot  = loss + 1;
    int*   bins  = (int*)(ws + 2539776);                 // 16,384
    float* esum  = (float*)(ws + 2556160);               // 2,097,152

    // zero loss/pad + bins + esum (contiguous)
    hipMemsetAsync(ws + 2539520, 0, 256 + 16384 + 2097152, stream);

    esplit_kernel<<<KCODES / 4, 256, 0, stream>>>(embed, estg, e2h);
    argmax_kernel<<<NROWS / 128, 512, 0, stream>>>(x, estg, e2h, ind, out_ind,
                                                   bins, loss);
    scan_kernel<<<1, 1024, 0, stream>>>(bins, cluster_size, loss, offsets, cursor,
                                        out_cs, ntot, out_loss);
    reorder_kernel<<<NROWS / 256, 256, 0, stream>>>(ind, cursor, rowids, codesorted);
    segred_kernel<<<NROWS / WROWS / 4, 256, 0, stream>>>(x, embed, rowids, codesorted,
                                                         offsets, bins, esum, out_q);
    norm_kernel<<<KCODES * DIM / 2 / 256, 256, 0, stream>>>(esum, embed_avg, out_cs,
                                                            ntot, out_norm);
}